// Round 1
// baseline (1159.110 us; speedup 1.0000x reference)
//
#include <hip/hip_runtime.h>

#define NSEQ 100000
#define NLAB 64
#define ECON 1600000
#define D 128
#define BN_EPS 1e-5f

// ---------------- helpers ----------------
__device__ __forceinline__ void atomAddF(float* p, float v) {
  // native global_atomic_add_f32 (no CAS loop); denorm semantics irrelevant here
  unsafeAtomicAdd(p, v);
}

// ---------------- degree / CSR build ----------------
__global__ __launch_bounds__(256) void k_edge_deg(const int* __restrict__ src,
                                                  const int* __restrict__ dst,
                                                  int* deg_out, int* deg_in) {
  int e = blockIdx.x * 256 + threadIdx.x;
  if (e < ECON) {
    atomicAdd(&deg_out[src[e]], 1);
    atomicAdd(&deg_in[dst[e]], 1);
  }
}

__global__ __launch_bounds__(256) void k_label_hist(const int* __restrict__ lab, int* cnt) {
  __shared__ int h[NLAB];
  if (threadIdx.x < NLAB) h[threadIdx.x] = 0;
  __syncthreads();
  for (int i = blockIdx.x * 256 + threadIdx.x; i < NSEQ; i += gridDim.x * 256)
    atomicAdd(&h[lab[i]], 1);
  __syncthreads();
  if (threadIdx.x < NLAB) atomicAdd(&cnt[threadIdx.x], h[threadIdx.x]);
}

__global__ __launch_bounds__(256) void k_dinv(const int* __restrict__ deg_out,
                                              const int* __restrict__ deg_in,
                                              const int* __restrict__ cnt,
                                              float* dinv_out, float* dinv_in,
                                              float* dinv_cnt) {
  int i = blockIdx.x * 256 + threadIdx.x;
  if (i < NSEQ) {
    int d0 = deg_out[i]; dinv_out[i] = d0 > 0 ? rsqrtf((float)d0) : 0.f;
    int d1 = deg_in[i];  dinv_in[i]  = d1 > 0 ? rsqrtf((float)d1) : 0.f;
  }
  if (i < NLAB) { int c = cnt[i]; dinv_cnt[i] = c > 0 ? rsqrtf((float)c) : 0.f; }
}

// offsets via per-wave prefix scan + one atomic per wave (range placement order
// is irrelevant to the final result)
__global__ __launch_bounds__(256) void k_offsets(const int* __restrict__ deg_in,
                                                 int* off, int* cursor, int* alloc) {
  int i = blockIdx.x * 256 + threadIdx.x;
  int lane = threadIdx.x & 63;
  int d = (i < NSEQ) ? deg_in[i] : 0;
  int v = d;
  #pragma unroll
  for (int o = 1; o < 64; o <<= 1) {
    int n = __shfl_up(v, o);
    if (lane >= o) v += n;
  }
  int total = __shfl(v, 63);
  int base = 0;
  if (lane == 63) base = atomicAdd(alloc, total);
  base = __shfl(base, 63);
  if (i < NSEQ) {
    int o = base + v - d;   // exclusive
    off[i] = o;
    cursor[i] = o;
  }
}

__global__ __launch_bounds__(256) void k_scatter(const int* __restrict__ src,
                                                 const int* __restrict__ dst,
                                                 int* cursor, int* esrc) {
  int e = blockIdx.x * 256 + threadIdx.x;
  if (e < ECON) {
    int p = atomicAdd(&cursor[dst[e]], 1);
    esrc[p] = src[e];
  }
}

// ---------------- label aggregation: lab_agg[l][f] = sum_{s: lab[s]==l} x[s][f]
__global__ __launch_bounds__(256) void k_label_agg(const float* __restrict__ x,
                                                   const int* __restrict__ lab,
                                                   float* lab_agg) {
  __shared__ float acc[NLAB * D];   // 32 KB
  for (int i = threadIdx.x; i < NLAB * D; i += 256) acc[i] = 0.f;
  __syncthreads();
  int f = threadIdx.x & (D - 1);
  int rsub = threadIdx.x >> 7;      // 0..1
  for (int r = blockIdx.x * 2 + rsub; r < NSEQ; r += gridDim.x * 2) {
    int l = lab[r];
    atomicAdd(&acc[l * D + f], x[r * D + f]);   // LDS ds_add_f32
  }
  __syncthreads();
  for (int i = threadIdx.x; i < NLAB * D; i += 256) atomAddF(&lab_agg[i], acc[i]);
}

// ---------------- small dense: label path (matmul+relu+BN) and y_inc ----------
__global__ __launch_bounds__(256) void k_small_dense(
    const float* __restrict__ lab_agg,   // 64x128
    const float* __restrict__ dinv_cnt,  // 64
    const float* __restrict__ W_bel,     // 128 x ncol
    const float* __restrict__ b_bel,     // ncol
    const float* __restrict__ g_l, const float* __restrict__ beta_l,
    float* __restrict__ out_l,           // 64 x ncol (post-BN)
    const float* __restrict__ src_inc,   // 64 x 128
    const float* __restrict__ W_inc,     // 128 x 128
    float* __restrict__ y_inc,           // 64 x 128 = src_inc @ W_inc
    int ncol) {
  __shared__ float sA[NLAB * D];   // dinv-scaled lab_agg
  __shared__ float sB[NLAB * D];   // src_inc, then reused as bel-matmul output
  int tid = threadIdx.x;
  for (int i = tid; i < NLAB * D; i += 256) {
    sA[i] = lab_agg[i] * dinv_cnt[i >> 7];
    sB[i] = src_inc[i];
  }
  __syncthreads();
  for (int o = tid; o < NLAB * D; o += 256) {
    int l = o >> 7, j = o & (D - 1);
    float s = 0.f;
    for (int k = 0; k < D; ++k) s = fmaf(sB[l * D + k], W_inc[k * D + j], s);
    y_inc[o] = s;
  }
  __syncthreads();   // all reads of sB done before reuse
  for (int o = tid; o < NLAB * ncol; o += 256) {
    int l = o / ncol, j = o - l * ncol;
    float s = b_bel[j];
    for (int k = 0; k < D; ++k) s = fmaf(sA[l * D + k], W_bel[k * ncol + j], s);
    sB[o] = fmaxf(s, 0.f);
  }
  __syncthreads();
  if (tid < ncol) {
    float m = 0.f;
    for (int l = 0; l < NLAB; ++l) m += sB[l * ncol + tid];
    m *= (1.f / NLAB);
    float v = 0.f;
    for (int l = 0; l < NLAB; ++l) { float dd = sB[l * ncol + tid] - m; v += dd * dd; }
    v *= (1.f / NLAB);
    float a = rsqrtf(v + BN_EPS) * g_l[tid];
    float c = beta_l[tid] - m * a;
    for (int l = 0; l < NLAB; ++l) out_l[l * ncol + tid] = sB[l * ncol + tid] * a + c;
  }
}

// ---------------- connected_to aggregation: one wave per dst row --------------
__global__ __launch_bounds__(256) void k_con_agg(
    const float* __restrict__ x, const int* __restrict__ esrc,
    const int* __restrict__ off, const int* __restrict__ endp,
    const float* __restrict__ dinv_out, const float* __restrict__ dinv_in,
    float* __restrict__ out) {
  int wid = (blockIdx.x * 256 + threadIdx.x) >> 6;   // dst node
  int lane = threadIdx.x & 63;
  if (wid >= NSEQ) return;
  int e0 = off[wid], e1 = endp[wid];
  const float2* xp = (const float2*)x;
  float ax = 0.f, ay = 0.f;
  int e = e0;
  for (; e + 1 < e1; e += 2) {      // 2-edge unroll for load ILP
    int s0 = esrc[e], s1 = esrc[e + 1];
    float w0 = dinv_out[s0], w1 = dinv_out[s1];
    float2 v0 = xp[s0 * 64 + lane];
    float2 v1 = xp[s1 * 64 + lane];
    ax += v0.x * w0 + v1.x * w1;
    ay += v0.y * w0 + v1.y * w1;
  }
  if (e < e1) {
    int s0 = esrc[e];
    float w0 = dinv_out[s0];
    float2 v0 = xp[s0 * 64 + lane];
    ax += v0.x * w0;
    ay += v0.y * w0;
  }
  float di = dinv_in[wid];
  float2 o; o.x = ax * di; o.y = ay * di;
  ((float2*)out)[wid * 64 + lane] = o;
}

// ---------------- GEMM (in-place) + epilogue + BN stats ----------------------
#define TILE_R 64
__global__ __launch_bounds__(256) void k_gemm_ep(
    float* __restrict__ buf,           // NSEQ x 128, in-place
    const float* __restrict__ W,       // 128x128
    const float* __restrict__ b_con,   // 128
    const float* __restrict__ y_inc,   // 64x128
    const float* __restrict__ b_inc,   // 128
    const float* __restrict__ dinv_cnt,
    const int* __restrict__ bel,
    float* __restrict__ stats) {       // [sum 128][sumsq 128]
  __shared__ float sA[TILE_R][D];      // 32 KB
  __shared__ float csum[D], csq[D];
  int tid = threadIdx.x;
  int row0 = blockIdx.x * TILE_R;
  for (int i = tid; i < TILE_R * D / 4; i += 256) {
    int r = i >> 5;
    int c = (i & 31) * 4;
    int row = row0 + r;
    float4 v = make_float4(0.f, 0.f, 0.f, 0.f);
    if (row < NSEQ) v = *(const float4*)&buf[row * D + c];
    *(float4*)&sA[r][c] = v;
  }
  if (tid < D) { csum[tid] = 0.f; csq[tid] = 0.f; }
  __syncthreads();

  int tx = tid & 31, ty = tid >> 5;
  int c0 = tx * 4, r0 = ty * 8;
  float acc[8][4];
  #pragma unroll
  for (int i = 0; i < 8; i++)
    #pragma unroll
    for (int j = 0; j < 4; j++) acc[i][j] = 0.f;

  for (int k = 0; k < D; ++k) {
    float4 w = *(const float4*)&W[k * D + c0];
    #pragma unroll
    for (int i = 0; i < 8; i++) {
      float a = sA[r0 + i][k];
      acc[i][0] = fmaf(a, w.x, acc[i][0]);
      acc[i][1] = fmaf(a, w.y, acc[i][1]);
      acc[i][2] = fmaf(a, w.z, acc[i][2]);
      acc[i][3] = fmaf(a, w.w, acc[i][3]);
    }
  }

  float4 bcn = *(const float4*)&b_con[c0];
  float4 bic = *(const float4*)&b_inc[c0];
  float ps[4] = {0.f, 0.f, 0.f, 0.f}, pq[4] = {0.f, 0.f, 0.f, 0.f};
  #pragma unroll
  for (int i = 0; i < 8; i++) {
    int row = row0 + r0 + i;
    if (row < NSEQ) {
      int l = bel[row];
      float dc = dinv_cnt[l];
      float4 yi = *(const float4*)&y_inc[l * D + c0];
      float o0 = fmaxf(0.5f * (acc[i][0] + bcn.x + fmaf(dc, yi.x, bic.x)), 0.f);
      float o1 = fmaxf(0.5f * (acc[i][1] + bcn.y + fmaf(dc, yi.y, bic.y)), 0.f);
      float o2 = fmaxf(0.5f * (acc[i][2] + bcn.z + fmaf(dc, yi.z, bic.z)), 0.f);
      float o3 = fmaxf(0.5f * (acc[i][3] + bcn.w + fmaf(dc, yi.w, bic.w)), 0.f);
      float4 o = make_float4(o0, o1, o2, o3);
      *(float4*)&buf[row * D + c0] = o;
      ps[0] += o0; ps[1] += o1; ps[2] += o2; ps[3] += o3;
      pq[0] += o0 * o0; pq[1] += o1 * o1; pq[2] += o2 * o2; pq[3] += o3 * o3;
    }
  }
  #pragma unroll
  for (int j = 0; j < 4; j++) {
    atomicAdd(&csum[c0 + j], ps[j]);
    atomicAdd(&csq[c0 + j], pq[j]);
  }
  __syncthreads();
  if (tid < D) {
    atomAddF(&stats[tid], csum[tid]);
    atomAddF(&stats[D + tid], csq[tid]);
  }
}

// ---------------- BN apply (elementwise, float4) -----------------------------
__global__ __launch_bounds__(256) void k_bn_apply(float* __restrict__ buf,
                                                  const float* __restrict__ stats,
                                                  const float* __restrict__ g,
                                                  const float* __restrict__ beta) {
  int i = blockIdx.x * 256 + threadIdx.x;     // float4 index
  if (i >= NSEQ * D / 4) return;
  int c = (i * 4) & (D - 1);
  float4 v = ((float4*)buf)[i];
  float4 s = *(const float4*)&stats[c];
  float4 q = *(const float4*)&stats[D + c];
  float4 gg = *(const float4*)&g[c];
  float4 bb = *(const float4*)&beta[c];
  const float invN = 1.f / (float)NSEQ;
  float m, var, a;
  m = s.x * invN; var = q.x * invN - m * m; a = rsqrtf(var + BN_EPS) * gg.x; v.x = (v.x - m) * a + bb.x;
  m = s.y * invN; var = q.y * invN - m * m; a = rsqrtf(var + BN_EPS) * gg.y; v.y = (v.y - m) * a + bb.y;
  m = s.z * invN; var = q.z * invN - m * m; a = rsqrtf(var + BN_EPS) * gg.z; v.z = (v.z - m) * a + bb.z;
  m = s.w * invN; var = q.w * invN - m * m; a = rsqrtf(var + BN_EPS) * gg.w; v.w = (v.w - m) * a + bb.w;
  ((float4*)buf)[i] = v;
}

// ---------------- launch ------------------------------------------------------
extern "C" void kernel_launch(void* const* d_in, const int* in_sizes, int n_in,
                              void* d_out, int out_size, void* d_ws, size_t ws_size,
                              hipStream_t stream) {
  const float* x_seq   = (const float*)d_in[0];
  const float* x_label = (const float*)d_in[1];
  const float* W1_bel  = (const float*)d_in[2];
  const float* b1_bel  = (const float*)d_in[3];
  const float* W1_inc  = (const float*)d_in[4];
  const float* b1_inc  = (const float*)d_in[5];
  const float* W1_con  = (const float*)d_in[6];
  const float* b1_con  = (const float*)d_in[7];
  const float* g1s     = (const float*)d_in[8];
  const float* beta1s  = (const float*)d_in[9];
  const float* g1l     = (const float*)d_in[10];
  const float* beta1l  = (const float*)d_in[11];
  const float* W2_bel  = (const float*)d_in[12];
  const float* b2_bel  = (const float*)d_in[13];
  const float* W2_inc  = (const float*)d_in[14];
  const float* b2_inc  = (const float*)d_in[15];
  const float* W2_con  = (const float*)d_in[16];
  const float* b2_con  = (const float*)d_in[17];
  const float* g2s     = (const float*)d_in[18];
  const float* beta2s  = (const float*)d_in[19];
  const float* g2l     = (const float*)d_in[20];
  const float* beta2l  = (const float*)d_in[21];
  const int* bel       = (const int*)d_in[22];
  const int* con_src   = (const int*)d_in[23];
  const int* con_dst   = (const int*)d_in[24];
  float* out = (float*)d_out;

  char* ws = (char*)d_ws;
  // workspace layout (~60.2 MB total)
  float* bufA     = (float*)(ws);                    // 51,200,000 B
  int*   esrc     = (int*)  (ws + 51200000);         //  6,400,000 B
  // ---- zeroed region start (868,864 B) ----
  int*   deg_out  = (int*)  (ws + 57600000);         //    400,000
  int*   deg_in   = (int*)  (ws + 58000000);         //    400,000
  int*   cnt_lab  = (int*)  (ws + 58400000);         //      1,024 (64 used)
  float* lab_agg1 = (float*)(ws + 58401024);         //     32,768
  float* lab_agg2 = (float*)(ws + 58433792);         //     32,768
  float* stats1   = (float*)(ws + 58466560);         //      1,024
  float* stats2   = (float*)(ws + 58467584);         //      1,024
  int*   alloc    = (int*)  (ws + 58468608);         //        256
  // ---- zeroed region end ----
  float* dinv_out = (float*)(ws + 58468864);
  float* dinv_in  = (float*)(ws + 58868864);
  float* dinv_cnt = (float*)(ws + 59268864);
  int*   off      = (int*)  (ws + 59269120);
  int*   cursor   = (int*)  (ws + 59669120);
  float* y_inc1   = (float*)(ws + 60069120);
  float* y_inc2   = (float*)(ws + 60101888);
  float* h_l1     = (float*)(ws + 60134656);
  // end: 60,167,424 B

  hipMemsetAsync(ws + 57600000, 0, 868864, stream);

  // degrees + CSR (shared by both layers)
  k_edge_deg  <<<(ECON + 255) / 256, 256, 0, stream>>>(con_src, con_dst, deg_out, deg_in);
  k_label_hist<<<256, 256, 0, stream>>>(bel, cnt_lab);
  k_dinv      <<<(NSEQ + 255) / 256, 256, 0, stream>>>(deg_out, deg_in, cnt_lab,
                                                       dinv_out, dinv_in, dinv_cnt);
  k_offsets   <<<(NSEQ + 255) / 256, 256, 0, stream>>>(deg_in, off, cursor, alloc);
  k_scatter   <<<(ECON + 255) / 256, 256, 0, stream>>>(con_src, con_dst, cursor, esrc);

  // ---- layer 1 ----
  k_label_agg  <<<512, 256, 0, stream>>>(x_seq, bel, lab_agg1);
  k_small_dense<<<1, 256, 0, stream>>>(lab_agg1, dinv_cnt, W1_bel, b1_bel, g1l, beta1l,
                                       h_l1, x_label, W1_inc, y_inc1, D);
  k_con_agg    <<<NSEQ / 4, 256, 0, stream>>>(x_seq, esrc, off, cursor,
                                              dinv_out, dinv_in, bufA);
  k_gemm_ep    <<<(NSEQ + TILE_R - 1) / TILE_R, 256, 0, stream>>>(
                   bufA, W1_con, b1_con, y_inc1, b1_inc, dinv_cnt, bel, stats1);
  k_bn_apply   <<<(NSEQ * D / 4 + 255) / 256, 256, 0, stream>>>(bufA, stats1, g1s, beta1s);

  // ---- layer 2 ----
  k_label_agg  <<<512, 256, 0, stream>>>(bufA, bel, lab_agg2);
  k_small_dense<<<1, 256, 0, stream>>>(lab_agg2, dinv_cnt, W2_bel, b2_bel, g2l, beta2l,
                                       out + (size_t)NSEQ * D, h_l1, W2_inc, y_inc2, 64);
  k_con_agg    <<<NSEQ / 4, 256, 0, stream>>>(bufA, esrc, off, cursor,
                                              dinv_out, dinv_in, out);
  k_gemm_ep    <<<(NSEQ + TILE_R - 1) / TILE_R, 256, 0, stream>>>(
                   out, W2_con, b2_con, y_inc2, b2_inc, dinv_cnt, bel, stats2);
  k_bn_apply   <<<(NSEQ * D / 4 + 255) / 256, 256, 0, stream>>>(out, stats2, g2s, beta2s);
}

// Round 2
// 970.712 us; speedup vs baseline: 1.1941x; 1.1941x over previous
//
#include <hip/hip_runtime.h>

#define NSEQ 100000
#define NLAB 64
#define ECON 1600000
#define D 128
#define BN_EPS 1e-5f

// ---------------- helpers ----------------
__device__ __forceinline__ void atomAddF(float* p, float v) {
  unsafeAtomicAdd(p, v);  // native global_atomic_add_f32
}

// ---------------- degree / CSR build ----------------
__global__ __launch_bounds__(256) void k_edge_deg(const int* __restrict__ src,
                                                  const int* __restrict__ dst,
                                                  int* deg_out, int* deg_in) {
  int e = blockIdx.x * 256 + threadIdx.x;
  if (e < ECON) {
    atomicAdd(&deg_out[src[e]], 1);
    atomicAdd(&deg_in[dst[e]], 1);
  }
}

__global__ __launch_bounds__(256) void k_label_hist(const int* __restrict__ lab, int* cnt) {
  __shared__ int h[NLAB];
  if (threadIdx.x < NLAB) h[threadIdx.x] = 0;
  __syncthreads();
  for (int i = blockIdx.x * 256 + threadIdx.x; i < NSEQ; i += gridDim.x * 256)
    atomicAdd(&h[lab[i]], 1);
  __syncthreads();
  if (threadIdx.x < NLAB) atomicAdd(&cnt[threadIdx.x], h[threadIdx.x]);
}

__global__ __launch_bounds__(256) void k_dinv(const int* __restrict__ deg_out,
                                              const int* __restrict__ deg_in,
                                              const int* __restrict__ cnt,
                                              float* dinv_out, float* dinv_in,
                                              float* dinv_cnt) {
  int i = blockIdx.x * 256 + threadIdx.x;
  if (i < NSEQ) {
    int d0 = deg_out[i]; dinv_out[i] = d0 > 0 ? rsqrtf((float)d0) : 0.f;
    int d1 = deg_in[i];  dinv_in[i]  = d1 > 0 ? rsqrtf((float)d1) : 0.f;
  }
  if (i < NLAB) { int c = cnt[i]; dinv_cnt[i] = c > 0 ? rsqrtf((float)c) : 0.f; }
}

// offsets via per-wave prefix scan + one atomic per wave
__global__ __launch_bounds__(256) void k_offsets(const int* __restrict__ deg_in,
                                                 int* off, int* cursor, int* alloc) {
  int i = blockIdx.x * 256 + threadIdx.x;
  int lane = threadIdx.x & 63;
  int d = (i < NSEQ) ? deg_in[i] : 0;
  int v = d;
  #pragma unroll
  for (int o = 1; o < 64; o <<= 1) {
    int n = __shfl_up(v, o);
    if (lane >= o) v += n;
  }
  int total = __shfl(v, 63);
  int base = 0;
  if (lane == 63) base = atomicAdd(alloc, total);
  base = __shfl(base, 63);
  if (i < NSEQ) {
    int o = base + v - d;   // exclusive
    off[i] = o;
    cursor[i] = o;
  }
}

__global__ __launch_bounds__(256) void k_scatter(const int* __restrict__ src,
                                                 const int* __restrict__ dst,
                                                 int* cursor, int* esrc) {
  int e = blockIdx.x * 256 + threadIdx.x;
  if (e < ECON) {
    int p = atomicAdd(&cursor[dst[e]], 1);
    esrc[p] = src[e];
  }
}

// ---------------- label aggregation: lab_agg[l][f] = sum_{s: lab[s]==l} x[s][f]
__global__ __launch_bounds__(256) void k_label_agg(const float* __restrict__ x,
                                                   const int* __restrict__ lab,
                                                   float* lab_agg) {
  __shared__ float acc[NLAB * D];   // 32 KB
  for (int i = threadIdx.x; i < NLAB * D; i += 256) acc[i] = 0.f;
  __syncthreads();
  int f = threadIdx.x & (D - 1);
  int rsub = threadIdx.x >> 7;      // 0..1
  for (int r = blockIdx.x * 2 + rsub; r < NSEQ; r += gridDim.x * 2) {
    int l = lab[r];
    atomicAdd(&acc[l * D + f], x[r * D + f]);   // LDS ds_add_f32
  }
  __syncthreads();
  for (int i = threadIdx.x; i < NLAB * D; i += 256) atomAddF(&lab_agg[i], acc[i]);
}

// ---------------- small matmul: out[64][ncol] = op((A*rowscale) @ W + bias) ---
// grid = 64 / (256/ncol) blocks, 256 threads
__global__ __launch_bounds__(256) void k_mm(
    const float* __restrict__ A,        // 64 x 128
    const float* __restrict__ rowscale, // 64 (or nullptr)
    const float* __restrict__ W,        // 128 x ncol
    const float* __restrict__ bias,     // ncol (or nullptr)
    float* __restrict__ out,            // 64 x ncol
    int ncol, int relu) {
  __shared__ float sA[4 * D];           // up to 4 rows
  int tid = threadIdx.x;
  int rows_pb = 256 / ncol;             // 2 (ncol=128) or 4 (ncol=64)
  int row0 = blockIdx.x * rows_pb;
  int nload = rows_pb * D;
  for (int i = tid; i < nload; i += 256) {
    int r = row0 + (i >> 7);
    float s = rowscale ? rowscale[r] : 1.f;
    sA[i] = A[r * D + (i & 127)] * s;
  }
  __syncthreads();
  int j = tid & (ncol - 1);
  int r = tid / ncol;
  const float* a = &sA[r * D];
  const float* w = &W[j];
  float acc0 = 0.f, acc1 = 0.f, acc2 = 0.f, acc3 = 0.f;
  #pragma unroll 4
  for (int k = 0; k < D; k += 4) {
    acc0 = fmaf(a[k + 0], w[(k + 0) * ncol], acc0);
    acc1 = fmaf(a[k + 1], w[(k + 1) * ncol], acc1);
    acc2 = fmaf(a[k + 2], w[(k + 2) * ncol], acc2);
    acc3 = fmaf(a[k + 3], w[(k + 3) * ncol], acc3);
  }
  float s = (acc0 + acc1) + (acc2 + acc3);
  if (bias) s += bias[j];
  if (relu) s = fmaxf(s, 0.f);
  out[(row0 + r) * ncol + j] = s;
}

// ---------------- BN over 64 label rows, then write post-BN -------------------
__global__ __launch_bounds__(256) void k_label_bn(
    const float* __restrict__ pre,   // 64 x ncol
    const float* __restrict__ g, const float* __restrict__ beta,
    float* __restrict__ out,         // 64 x ncol
    int ncol) {
  __shared__ float psum[256], psq[256];
  __shared__ float sa[128], sc[128];
  int tid = threadIdx.x;
  int ngrp = 256 / ncol;
  int grp = tid / ncol;
  int col = tid & (ncol - 1);
  float s = 0.f, q = 0.f;
  for (int r = grp; r < NLAB; r += ngrp) {
    float v = pre[r * ncol + col];
    s += v; q += v * v;
  }
  psum[tid] = s; psq[tid] = q;
  __syncthreads();
  if (tid < ncol) {
    float S = 0.f, Q = 0.f;
    for (int gi = 0; gi < ngrp; ++gi) { S += psum[gi * ncol + tid]; Q += psq[gi * ncol + tid]; }
    float m = S * (1.f / NLAB);
    float v = Q * (1.f / NLAB) - m * m;
    float a = rsqrtf(v + BN_EPS) * g[tid];
    sa[tid] = a; sc[tid] = beta[tid] - m * a;
  }
  __syncthreads();
  for (int i = tid; i < NLAB * ncol; i += 256) {
    int c = i & (ncol - 1);
    out[i] = pre[i] * sa[c] + sc[c];
  }
}

// ---------------- connected_to aggregation: one wave per dst row --------------
__global__ __launch_bounds__(256) void k_con_agg(
    const float* __restrict__ x, const int* __restrict__ esrc,
    const int* __restrict__ off, const int* __restrict__ endp,
    const float* __restrict__ dinv_out, const float* __restrict__ dinv_in,
    float* __restrict__ out) {
  int wid = (blockIdx.x * 256 + threadIdx.x) >> 6;   // dst node
  int lane = threadIdx.x & 63;
  if (wid >= NSEQ) return;
  int e0 = off[wid], e1 = endp[wid];
  const float2* xp = (const float2*)x;
  float ax = 0.f, ay = 0.f;
  int e = e0;
  for (; e + 1 < e1; e += 2) {      // 2-edge unroll for load ILP
    int s0 = esrc[e], s1 = esrc[e + 1];
    float w0 = dinv_out[s0], w1 = dinv_out[s1];
    float2 v0 = xp[s0 * 64 + lane];
    float2 v1 = xp[s1 * 64 + lane];
    ax += v0.x * w0 + v1.x * w1;
    ay += v0.y * w0 + v1.y * w1;
  }
  if (e < e1) {
    int s0 = esrc[e];
    float w0 = dinv_out[s0];
    float2 v0 = xp[s0 * 64 + lane];
    ax += v0.x * w0;
    ay += v0.y * w0;
  }
  float di = dinv_in[wid];
  float2 o; o.x = ax * di; o.y = ay * di;
  ((float2*)out)[wid * 64 + lane] = o;
}

// ---------------- GEMM (in-place) + epilogue + BN stats ----------------------
#define TILE_R 64
__global__ __launch_bounds__(256) void k_gemm_ep(
    float* __restrict__ buf,           // NSEQ x 128, in-place
    const float* __restrict__ W,       // 128x128
    const float* __restrict__ b_con,   // 128
    const float* __restrict__ y_inc,   // 64x128
    const float* __restrict__ b_inc,   // 128
    const float* __restrict__ dinv_cnt,
    const int* __restrict__ bel,
    float* __restrict__ stats) {       // [sum 128][sumsq 128]
  __shared__ float sA[TILE_R][D];      // 32 KB
  __shared__ float csum[D], csq[D];
  int tid = threadIdx.x;
  int row0 = blockIdx.x * TILE_R;
  for (int i = tid; i < TILE_R * D / 4; i += 256) {
    int r = i >> 5;
    int c = (i & 31) * 4;
    int row = row0 + r;
    float4 v = make_float4(0.f, 0.f, 0.f, 0.f);
    if (row < NSEQ) v = *(const float4*)&buf[row * D + c];
    *(float4*)&sA[r][c] = v;
  }
  if (tid < D) { csum[tid] = 0.f; csq[tid] = 0.f; }
  __syncthreads();

  int tx = tid & 31, ty = tid >> 5;
  int c0 = tx * 4, r0 = ty * 8;
  float acc[8][4];
  #pragma unroll
  for (int i = 0; i < 8; i++)
    #pragma unroll
    for (int j = 0; j < 4; j++) acc[i][j] = 0.f;

  for (int k = 0; k < D; ++k) {
    float4 w = *(const float4*)&W[k * D + c0];
    #pragma unroll
    for (int i = 0; i < 8; i++) {
      float a = sA[r0 + i][k];
      acc[i][0] = fmaf(a, w.x, acc[i][0]);
      acc[i][1] = fmaf(a, w.y, acc[i][1]);
      acc[i][2] = fmaf(a, w.z, acc[i][2]);
      acc[i][3] = fmaf(a, w.w, acc[i][3]);
    }
  }

  float4 bcn = *(const float4*)&b_con[c0];
  float4 bic = *(const float4*)&b_inc[c0];
  float ps[4] = {0.f, 0.f, 0.f, 0.f}, pq[4] = {0.f, 0.f, 0.f, 0.f};
  #pragma unroll
  for (int i = 0; i < 8; i++) {
    int row = row0 + r0 + i;
    if (row < NSEQ) {
      int l = bel[row];
      float dc = dinv_cnt[l];
      float4 yi = *(const float4*)&y_inc[l * D + c0];
      float o0 = fmaxf(0.5f * (acc[i][0] + bcn.x + fmaf(dc, yi.x, bic.x)), 0.f);
      float o1 = fmaxf(0.5f * (acc[i][1] + bcn.y + fmaf(dc, yi.y, bic.y)), 0.f);
      float o2 = fmaxf(0.5f * (acc[i][2] + bcn.z + fmaf(dc, yi.z, bic.z)), 0.f);
      float o3 = fmaxf(0.5f * (acc[i][3] + bcn.w + fmaf(dc, yi.w, bic.w)), 0.f);
      float4 o = make_float4(o0, o1, o2, o3);
      *(float4*)&buf[row * D + c0] = o;
      ps[0] += o0; ps[1] += o1; ps[2] += o2; ps[3] += o3;
      pq[0] += o0 * o0; pq[1] += o1 * o1; pq[2] += o2 * o2; pq[3] += o3 * o3;
    }
  }
  #pragma unroll
  for (int j = 0; j < 4; j++) {
    atomicAdd(&csum[c0 + j], ps[j]);
    atomicAdd(&csq[c0 + j], pq[j]);
  }
  __syncthreads();
  if (tid < D) {
    atomAddF(&stats[tid], csum[tid]);
    atomAddF(&stats[D + tid], csq[tid]);
  }
}

// ---------------- BN apply (elementwise, float4) -----------------------------
__global__ __launch_bounds__(256) void k_bn_apply(float* __restrict__ buf,
                                                  const float* __restrict__ stats,
                                                  const float* __restrict__ g,
                                                  const float* __restrict__ beta) {
  int i = blockIdx.x * 256 + threadIdx.x;     // float4 index
  if (i >= NSEQ * D / 4) return;
  int c = (i * 4) & (D - 1);
  float4 v = ((float4*)buf)[i];
  float4 s = *(const float4*)&stats[c];
  float4 q = *(const float4*)&stats[D + c];
  float4 gg = *(const float4*)&g[c];
  float4 bb = *(const float4*)&beta[c];
  const float invN = 1.f / (float)NSEQ;
  float m, var, a;
  m = s.x * invN; var = q.x * invN - m * m; a = rsqrtf(var + BN_EPS) * gg.x; v.x = (v.x - m) * a + bb.x;
  m = s.y * invN; var = q.y * invN - m * m; a = rsqrtf(var + BN_EPS) * gg.y; v.y = (v.y - m) * a + bb.y;
  m = s.z * invN; var = q.z * invN - m * m; a = rsqrtf(var + BN_EPS) * gg.z; v.z = (v.z - m) * a + bb.z;
  m = s.w * invN; var = q.w * invN - m * m; a = rsqrtf(var + BN_EPS) * gg.w; v.w = (v.w - m) * a + bb.w;
  ((float4*)buf)[i] = v;
}

// ---------------- launch ------------------------------------------------------
extern "C" void kernel_launch(void* const* d_in, const int* in_sizes, int n_in,
                              void* d_out, int out_size, void* d_ws, size_t ws_size,
                              hipStream_t stream) {
  const float* x_seq   = (const float*)d_in[0];
  const float* x_label = (const float*)d_in[1];
  const float* W1_bel  = (const float*)d_in[2];
  const float* b1_bel  = (const float*)d_in[3];
  const float* W1_inc  = (const float*)d_in[4];
  const float* b1_inc  = (const float*)d_in[5];
  const float* W1_con  = (const float*)d_in[6];
  const float* b1_con  = (const float*)d_in[7];
  const float* g1s     = (const float*)d_in[8];
  const float* beta1s  = (const float*)d_in[9];
  const float* g1l     = (const float*)d_in[10];
  const float* beta1l  = (const float*)d_in[11];
  const float* W2_bel  = (const float*)d_in[12];
  const float* b2_bel  = (const float*)d_in[13];
  const float* W2_inc  = (const float*)d_in[14];
  const float* b2_inc  = (const float*)d_in[15];
  const float* W2_con  = (const float*)d_in[16];
  const float* b2_con  = (const float*)d_in[17];
  const float* g2s     = (const float*)d_in[18];
  const float* beta2s  = (const float*)d_in[19];
  const float* g2l     = (const float*)d_in[20];
  const float* beta2l  = (const float*)d_in[21];
  const int* bel       = (const int*)d_in[22];
  const int* con_src   = (const int*)d_in[23];
  const int* con_dst   = (const int*)d_in[24];
  float* out = (float*)d_out;

  char* ws = (char*)d_ws;
  float* bufA     = (float*)(ws);                    // 51,200,000 B
  int*   esrc     = (int*)  (ws + 51200000);         //  6,400,000 B
  // ---- zeroed region start (868,864 B) ----
  int*   deg_out  = (int*)  (ws + 57600000);
  int*   deg_in   = (int*)  (ws + 58000000);
  int*   cnt_lab  = (int*)  (ws + 58400000);
  float* lab_agg1 = (float*)(ws + 58401024);
  float* lab_agg2 = (float*)(ws + 58433792);
  float* stats1   = (float*)(ws + 58466560);
  float* stats2   = (float*)(ws + 58467584);
  int*   alloc    = (int*)  (ws + 58468608);
  // ---- zeroed region end ----
  float* dinv_out = (float*)(ws + 58468864);
  float* dinv_in  = (float*)(ws + 58868864);
  float* dinv_cnt = (float*)(ws + 59268864);
  int*   off      = (int*)  (ws + 59269120);
  int*   cursor   = (int*)  (ws + 59669120);
  float* y_inc1   = (float*)(ws + 60069120);
  float* y_inc2   = (float*)(ws + 60101888);
  float* h_l1     = (float*)(ws + 60134656);
  // end: 60,167,424 B

  // bel-pre scratch lives in regions overwritten later in stream order:
  float* belp1 = bufA;   // overwritten by k_con_agg (layer 1) afterwards
  float* belp2 = out;    // overwritten by k_con_agg (layer 2) afterwards

  hipMemsetAsync(ws + 57600000, 0, 868864, stream);

  // degrees + CSR (shared by both layers)
  k_edge_deg  <<<(ECON + 255) / 256, 256, 0, stream>>>(con_src, con_dst, deg_out, deg_in);
  k_label_hist<<<256, 256, 0, stream>>>(bel, cnt_lab);
  k_dinv      <<<(NSEQ + 255) / 256, 256, 0, stream>>>(deg_out, deg_in, cnt_lab,
                                                       dinv_out, dinv_in, dinv_cnt);
  k_offsets   <<<(NSEQ + 255) / 256, 256, 0, stream>>>(deg_in, off, cursor, alloc);
  k_scatter   <<<(ECON + 255) / 256, 256, 0, stream>>>(con_src, con_dst, cursor, esrc);

  // ---- layer 1 ----
  k_label_agg <<<512, 256, 0, stream>>>(x_seq, bel, lab_agg1);
  k_mm        <<<32, 256, 0, stream>>>(x_label, nullptr, W1_inc, nullptr, y_inc1, 128, 0);
  k_mm        <<<32, 256, 0, stream>>>(lab_agg1, dinv_cnt, W1_bel, b1_bel, belp1, 128, 1);
  k_label_bn  <<<1, 256, 0, stream>>>(belp1, g1l, beta1l, h_l1, 128);
  k_con_agg   <<<NSEQ / 4, 256, 0, stream>>>(x_seq, esrc, off, cursor,
                                             dinv_out, dinv_in, bufA);
  k_gemm_ep   <<<(NSEQ + TILE_R - 1) / TILE_R, 256, 0, stream>>>(
                  bufA, W1_con, b1_con, y_inc1, b1_inc, dinv_cnt, bel, stats1);
  k_bn_apply  <<<(NSEQ * D / 4 + 255) / 256, 256, 0, stream>>>(bufA, stats1, g1s, beta1s);

  // ---- layer 2 ----
  k_label_agg <<<512, 256, 0, stream>>>(bufA, bel, lab_agg2);
  k_mm        <<<32, 256, 0, stream>>>(h_l1, nullptr, W2_inc, nullptr, y_inc2, 128, 0);
  k_mm        <<<16, 256, 0, stream>>>(lab_agg2, dinv_cnt, W2_bel, b2_bel, belp2, 64, 1);
  k_label_bn  <<<1, 256, 0, stream>>>(belp2, g2l, beta2l, out + (size_t)NSEQ * D, 64);
  k_con_agg   <<<NSEQ / 4, 256, 0, stream>>>(bufA, esrc, off, cursor,
                                             dinv_out, dinv_in, out);
  k_gemm_ep   <<<(NSEQ + TILE_R - 1) / TILE_R, 256, 0, stream>>>(
                  out, W2_con, b2_con, y_inc2, b2_inc, dinv_cnt, bel, stats2);
  k_bn_apply  <<<(NSEQ * D / 4 + 255) / 256, 256, 0, stream>>>(out, stats2, g2s, beta2s);
}

// Round 3
// 833.521 us; speedup vs baseline: 1.3906x; 1.1646x over previous
//
#include <hip/hip_runtime.h>
#include <hip/hip_bf16.h>

#define NSEQ 100000
#define NLAB 64
#define ECON 1600000
#define D 128
#define BN_EPS 1e-5f

typedef unsigned int uint32;

// ---------------- helpers ----------------
__device__ __forceinline__ void atomAddF(float* p, float v) {
  unsafeAtomicAdd(p, v);  // native global_atomic_add_f32
}
__device__ __forceinline__ float blo(uint32 u) {
  union { uint32 u; float f; } c; c.u = u << 16; return c.f;
}
__device__ __forceinline__ float bhi(uint32 u) {
  union { uint32 u; float f; } c; c.u = u & 0xFFFF0000u; return c.f;
}
__device__ __forceinline__ unsigned short f2b(float f) {
  __hip_bfloat16 h = __float2bfloat16(f);   // RNE
  union { __hip_bfloat16 h; unsigned short s; } c; c.h = h; return c.s;
}

// ---------------- degree / CSR build ----------------
__global__ __launch_bounds__(256) void k_edge_deg(const int* __restrict__ src,
                                                  const int* __restrict__ dst,
                                                  int* deg_out, int* deg_in) {
  int e = blockIdx.x * 256 + threadIdx.x;
  if (e < ECON) {
    atomicAdd(&deg_out[src[e]], 1);
    atomicAdd(&deg_in[dst[e]], 1);
  }
}

__global__ __launch_bounds__(256) void k_label_hist(const int* __restrict__ lab, int* cnt) {
  __shared__ int h[NLAB];
  if (threadIdx.x < NLAB) h[threadIdx.x] = 0;
  __syncthreads();
  for (int i = blockIdx.x * 256 + threadIdx.x; i < NSEQ; i += gridDim.x * 256)
    atomicAdd(&h[lab[i]], 1);
  __syncthreads();
  if (threadIdx.x < NLAB) atomicAdd(&cnt[threadIdx.x], h[threadIdx.x]);
}

// offsets (wave scan + one atomic per wave) fused with dinv computation
__global__ __launch_bounds__(256) void k_offsets(const int* __restrict__ deg_in,
                                                 const int* __restrict__ deg_out,
                                                 const int* __restrict__ cnt,
                                                 int* off, int* cursor, int* alloc,
                                                 float* dinv_out, float* dinv_in,
                                                 float* dinv_cnt) {
  int i = blockIdx.x * 256 + threadIdx.x;
  int lane = threadIdx.x & 63;
  int d = (i < NSEQ) ? deg_in[i] : 0;
  if (i < NSEQ) {
    int d0 = deg_out[i];
    dinv_out[i] = d0 > 0 ? rsqrtf((float)d0) : 0.f;
    dinv_in[i]  = d  > 0 ? rsqrtf((float)d)  : 0.f;
  }
  if (i < NLAB) { int c = cnt[i]; dinv_cnt[i] = c > 0 ? rsqrtf((float)c) : 0.f; }
  int v = d;
  #pragma unroll
  for (int o = 1; o < 64; o <<= 1) {
    int n = __shfl_up(v, o);
    if (lane >= o) v += n;
  }
  int total = __shfl(v, 63);
  int base = 0;
  if (lane == 63) base = atomicAdd(alloc, total);
  base = __shfl(base, 63);
  if (i < NSEQ) {
    int o = base + v - d;   // exclusive
    off[i] = o;
    cursor[i] = o;
  }
}

__global__ __launch_bounds__(256) void k_scatter(const int* __restrict__ src,
                                                 const int* __restrict__ dst,
                                                 int* cursor, int* esrc) {
  int e = blockIdx.x * 256 + threadIdx.x;
  if (e < ECON) {
    int p = atomicAdd(&cursor[dst[e]], 1);
    esrc[p] = src[e];
  }
}

// ---------------- fp32 -> bf16 cast (float4 -> 4 bf16) -----------------------
__global__ __launch_bounds__(256) void k_cast(const float* __restrict__ x,
                                              uint32* __restrict__ xb) {
  int i = blockIdx.x * 256 + threadIdx.x;     // float4 index
  if (i >= NSEQ * D / 4) return;
  float4 v = ((const float4*)x)[i];
  uint32 u0 = (uint32)f2b(v.x) | ((uint32)f2b(v.y) << 16);
  uint32 u1 = (uint32)f2b(v.z) | ((uint32)f2b(v.w) << 16);
  ((uint2*)xb)[i] = make_uint2(u0, u1);
}

// ---------------- label aggregation from bf16 --------------------------------
__global__ __launch_bounds__(256) void k_label_agg(const uint32* __restrict__ xb,
                                                   const int* __restrict__ lab,
                                                   float* lab_agg) {
  __shared__ float acc[NLAB * D];   // 32 KB
  for (int i = threadIdx.x; i < NLAB * D; i += 256) acc[i] = 0.f;
  __syncthreads();
  int cp = threadIdx.x & 63;        // col pair
  int rsub = threadIdx.x >> 6;      // 0..3
  for (int r = blockIdx.x * 4 + rsub; r < NSEQ; r += gridDim.x * 4) {
    int l = lab[r];
    uint32 u = xb[r * 64 + cp];
    atomicAdd(&acc[l * D + 2 * cp], blo(u));
    atomicAdd(&acc[l * D + 2 * cp + 1], bhi(u));
  }
  __syncthreads();
  for (int i = threadIdx.x; i < NLAB * D; i += 256) atomAddF(&lab_agg[i], acc[i]);
}

// ---------------- small matmul: out[64][ncol] = op((A*rowscale) @ W + bias) ---
__global__ __launch_bounds__(256) void k_mm(
    const float* __restrict__ A,        // 64 x 128
    const float* __restrict__ rowscale, // 64 (or nullptr)
    const float* __restrict__ W,        // 128 x ncol
    const float* __restrict__ bias,     // ncol (or nullptr)
    float* __restrict__ out,            // 64 x ncol
    int ncol, int relu) {
  __shared__ float sA[4 * D];
  int tid = threadIdx.x;
  int rows_pb = 256 / ncol;
  int row0 = blockIdx.x * rows_pb;
  int nload = rows_pb * D;
  for (int i = tid; i < nload; i += 256) {
    int r = row0 + (i >> 7);
    float s = rowscale ? rowscale[r] : 1.f;
    sA[i] = A[r * D + (i & 127)] * s;
  }
  __syncthreads();
  int j = tid & (ncol - 1);
  int r = tid / ncol;
  const float* a = &sA[r * D];
  const float* w = &W[j];
  float acc0 = 0.f, acc1 = 0.f, acc2 = 0.f, acc3 = 0.f;
  #pragma unroll 4
  for (int k = 0; k < D; k += 4) {
    acc0 = fmaf(a[k + 0], w[(k + 0) * ncol], acc0);
    acc1 = fmaf(a[k + 1], w[(k + 1) * ncol], acc1);
    acc2 = fmaf(a[k + 2], w[(k + 2) * ncol], acc2);
    acc3 = fmaf(a[k + 3], w[(k + 3) * ncol], acc3);
  }
  float s = (acc0 + acc1) + (acc2 + acc3);
  if (bias) s += bias[j];
  if (relu) s = fmaxf(s, 0.f);
  out[(row0 + r) * ncol + j] = s;
}

// ---------------- BN over 64 label rows --------------------------------------
__global__ __launch_bounds__(256) void k_label_bn(
    const float* __restrict__ pre,   // 64 x ncol
    const float* __restrict__ g, const float* __restrict__ beta,
    float* __restrict__ out,         // 64 x ncol
    int ncol) {
  __shared__ float psum[256], psq[256];
  __shared__ float sa[128], sc[128];
  int tid = threadIdx.x;
  int ngrp = 256 / ncol;
  int grp = tid / ncol;
  int col = tid & (ncol - 1);
  float s = 0.f, q = 0.f;
  for (int r = grp; r < NLAB; r += ngrp) {
    float v = pre[r * ncol + col];
    s += v; q += v * v;
  }
  psum[tid] = s; psq[tid] = q;
  __syncthreads();
  if (tid < ncol) {
    float S = 0.f, Q = 0.f;
    for (int gi = 0; gi < ngrp; ++gi) { S += psum[gi * ncol + tid]; Q += psq[gi * ncol + tid]; }
    float m = S * (1.f / NLAB);
    float v = Q * (1.f / NLAB) - m * m;
    float a = rsqrtf(v + BN_EPS) * g[tid];
    sa[tid] = a; sc[tid] = beta[tid] - m * a;
  }
  __syncthreads();
  for (int i = tid; i < NLAB * ncol; i += 256) {
    int c = i & (ncol - 1);
    out[i] = pre[i] * sa[c] + sc[c];
  }
}

// ---------------- connected_to aggregation from bf16: one wave per dst row ----
__global__ __launch_bounds__(256) void k_con_agg_bf(
    const uint32* __restrict__ xb, const int* __restrict__ esrc,
    const int* __restrict__ off, const int* __restrict__ endp,
    const float* __restrict__ dinv_out, const float* __restrict__ dinv_in,
    float* __restrict__ out) {
  int wid = (blockIdx.x * 256 + threadIdx.x) >> 6;   // dst node
  int lane = threadIdx.x & 63;
  if (wid >= NSEQ) return;
  int e0 = off[wid], e1 = endp[wid];
  float ax = 0.f, ay = 0.f;
  int e = e0;
  for (; e + 3 < e1; e += 4) {      // 4-edge unroll for load ILP
    int s0 = esrc[e], s1 = esrc[e + 1], s2 = esrc[e + 2], s3 = esrc[e + 3];
    float w0 = dinv_out[s0], w1 = dinv_out[s1], w2 = dinv_out[s2], w3 = dinv_out[s3];
    uint32 u0 = xb[s0 * 64 + lane];
    uint32 u1 = xb[s1 * 64 + lane];
    uint32 u2 = xb[s2 * 64 + lane];
    uint32 u3 = xb[s3 * 64 + lane];
    ax += blo(u0) * w0 + blo(u1) * w1 + blo(u2) * w2 + blo(u3) * w3;
    ay += bhi(u0) * w0 + bhi(u1) * w1 + bhi(u2) * w2 + bhi(u3) * w3;
  }
  for (; e < e1; ++e) {
    int s0 = esrc[e];
    float w0 = dinv_out[s0];
    uint32 u0 = xb[s0 * 64 + lane];
    ax += blo(u0) * w0;
    ay += bhi(u0) * w0;
  }
  float di = dinv_in[wid];
  float2 o; o.x = ax * di; o.y = ay * di;
  ((float2*)out)[wid * 64 + lane] = o;
}

// ---------------- GEMM + epilogue + BN stats ----------------------------------
#define TILE_R 64
__global__ __launch_bounds__(256) void k_gemm_ep(
    const float* __restrict__ bufIn,   // NSEQ x 128 (agg)
    float* __restrict__ bufOut,        // NSEQ x 128 (pre-BN h, may alias bufIn)
    const float* __restrict__ W,       // 128x128
    const float* __restrict__ b_con,   // 128
    const float* __restrict__ y_inc,   // 64x128
    const float* __restrict__ b_inc,   // 128
    const float* __restrict__ dinv_cnt,
    const int* __restrict__ bel,
    float* __restrict__ stats) {       // [sum 128][sumsq 128]
  __shared__ float sA[TILE_R][D];      // 32 KB
  __shared__ float csum[D], csq[D];
  int tid = threadIdx.x;
  int row0 = blockIdx.x * TILE_R;
  for (int i = tid; i < TILE_R * D / 4; i += 256) {
    int r = i >> 5;
    int c = (i & 31) * 4;
    int row = row0 + r;
    float4 v = make_float4(0.f, 0.f, 0.f, 0.f);
    if (row < NSEQ) v = *(const float4*)&bufIn[row * D + c];
    *(float4*)&sA[r][c] = v;
  }
  if (tid < D) { csum[tid] = 0.f; csq[tid] = 0.f; }
  __syncthreads();

  int tx = tid & 31, ty = tid >> 5;
  int c0 = tx * 4, r0 = ty * 8;
  float acc[8][4];
  #pragma unroll
  for (int i = 0; i < 8; i++)
    #pragma unroll
    for (int j = 0; j < 4; j++) acc[i][j] = 0.f;

  for (int k = 0; k < D; k += 4) {
    float4 w0 = *(const float4*)&W[(k + 0) * D + c0];
    float4 w1 = *(const float4*)&W[(k + 1) * D + c0];
    float4 w2 = *(const float4*)&W[(k + 2) * D + c0];
    float4 w3 = *(const float4*)&W[(k + 3) * D + c0];
    #pragma unroll
    for (int i = 0; i < 8; i++) {
      float4 a = *(const float4*)&sA[r0 + i][k];   // ds_read_b128
      acc[i][0] = fmaf(a.x, w0.x, acc[i][0]);
      acc[i][1] = fmaf(a.x, w0.y, acc[i][1]);
      acc[i][2] = fmaf(a.x, w0.z, acc[i][2]);
      acc[i][3] = fmaf(a.x, w0.w, acc[i][3]);
      acc[i][0] = fmaf(a.y, w1.x, acc[i][0]);
      acc[i][1] = fmaf(a.y, w1.y, acc[i][1]);
      acc[i][2] = fmaf(a.y, w1.z, acc[i][2]);
      acc[i][3] = fmaf(a.y, w1.w, acc[i][3]);
      acc[i][0] = fmaf(a.z, w2.x, acc[i][0]);
      acc[i][1] = fmaf(a.z, w2.y, acc[i][1]);
      acc[i][2] = fmaf(a.z, w2.z, acc[i][2]);
      acc[i][3] = fmaf(a.z, w2.w, acc[i][3]);
      acc[i][0] = fmaf(a.w, w3.x, acc[i][0]);
      acc[i][1] = fmaf(a.w, w3.y, acc[i][1]);
      acc[i][2] = fmaf(a.w, w3.z, acc[i][2]);
      acc[i][3] = fmaf(a.w, w3.w, acc[i][3]);
    }
  }

  float4 bcn = *(const float4*)&b_con[c0];
  float4 bic = *(const float4*)&b_inc[c0];
  float ps[4] = {0.f, 0.f, 0.f, 0.f}, pq[4] = {0.f, 0.f, 0.f, 0.f};
  #pragma unroll
  for (int i = 0; i < 8; i++) {
    int row = row0 + r0 + i;
    if (row < NSEQ) {
      int l = bel[row];
      float dc = dinv_cnt[l];
      float4 yi = *(const float4*)&y_inc[l * D + c0];
      float o0 = fmaxf(0.5f * (acc[i][0] + bcn.x + fmaf(dc, yi.x, bic.x)), 0.f);
      float o1 = fmaxf(0.5f * (acc[i][1] + bcn.y + fmaf(dc, yi.y, bic.y)), 0.f);
      float o2 = fmaxf(0.5f * (acc[i][2] + bcn.z + fmaf(dc, yi.z, bic.z)), 0.f);
      float o3 = fmaxf(0.5f * (acc[i][3] + bcn.w + fmaf(dc, yi.w, bic.w)), 0.f);
      *(float4*)&bufOut[row * D + c0] = make_float4(o0, o1, o2, o3);
      ps[0] += o0; ps[1] += o1; ps[2] += o2; ps[3] += o3;
      pq[0] += o0 * o0; pq[1] += o1 * o1; pq[2] += o2 * o2; pq[3] += o3 * o3;
    }
  }
  #pragma unroll
  for (int j = 0; j < 4; j++) {
    atomicAdd(&csum[c0 + j], ps[j]);
    atomicAdd(&csq[c0 + j], pq[j]);
  }
  __syncthreads();
  if (tid < D) {
    atomAddF(&stats[tid], csum[tid]);
    atomAddF(&stats[D + tid], csq[tid]);
  }
}

// ---------------- BN apply + cast to bf16 (layer 1) ---------------------------
__global__ __launch_bounds__(256) void k_bn_apply_cast(
    const float* __restrict__ buf, const float* __restrict__ stats,
    const float* __restrict__ g, const float* __restrict__ beta,
    uint32* __restrict__ xb) {
  int i = blockIdx.x * 256 + threadIdx.x;     // float4 index
  if (i >= NSEQ * D / 4) return;
  int c = (i * 4) & (D - 1);
  float4 v = ((const float4*)buf)[i];
  float4 s = *(const float4*)&stats[c];
  float4 q = *(const float4*)&stats[D + c];
  float4 gg = *(const float4*)&g[c];
  float4 bb = *(const float4*)&beta[c];
  const float invN = 1.f / (float)NSEQ;
  float m, var, a;
  m = s.x * invN; var = q.x * invN - m * m; a = rsqrtf(var + BN_EPS) * gg.x; v.x = (v.x - m) * a + bb.x;
  m = s.y * invN; var = q.y * invN - m * m; a = rsqrtf(var + BN_EPS) * gg.y; v.y = (v.y - m) * a + bb.y;
  m = s.z * invN; var = q.z * invN - m * m; a = rsqrtf(var + BN_EPS) * gg.z; v.z = (v.z - m) * a + bb.z;
  m = s.w * invN; var = q.w * invN - m * m; a = rsqrtf(var + BN_EPS) * gg.w; v.w = (v.w - m) * a + bb.w;
  uint32 u0 = (uint32)f2b(v.x) | ((uint32)f2b(v.y) << 16);
  uint32 u1 = (uint32)f2b(v.z) | ((uint32)f2b(v.w) << 16);
  ((uint2*)xb)[i] = make_uint2(u0, u1);
}

// ---------------- BN apply (final, fp32 in place) ------------------------------
__global__ __launch_bounds__(256) void k_bn_apply(float* __restrict__ buf,
                                                  const float* __restrict__ stats,
                                                  const float* __restrict__ g,
                                                  const float* __restrict__ beta) {
  int i = blockIdx.x * 256 + threadIdx.x;     // float4 index
  if (i >= NSEQ * D / 4) return;
  int c = (i * 4) & (D - 1);
  float4 v = ((float4*)buf)[i];
  float4 s = *(const float4*)&stats[c];
  float4 q = *(const float4*)&stats[D + c];
  float4 gg = *(const float4*)&g[c];
  float4 bb = *(const float4*)&beta[c];
  const float invN = 1.f / (float)NSEQ;
  float m, var, a;
  m = s.x * invN; var = q.x * invN - m * m; a = rsqrtf(var + BN_EPS) * gg.x; v.x = (v.x - m) * a + bb.x;
  m = s.y * invN; var = q.y * invN - m * m; a = rsqrtf(var + BN_EPS) * gg.y; v.y = (v.y - m) * a + bb.y;
  m = s.z * invN; var = q.z * invN - m * m; a = rsqrtf(var + BN_EPS) * gg.z; v.z = (v.z - m) * a + bb.z;
  m = s.w * invN; var = q.w * invN - m * m; a = rsqrtf(var + BN_EPS) * gg.w; v.w = (v.w - m) * a + bb.w;
  ((float4*)buf)[i] = v;
}

// ---------------- launch ------------------------------------------------------
extern "C" void kernel_launch(void* const* d_in, const int* in_sizes, int n_in,
                              void* d_out, int out_size, void* d_ws, size_t ws_size,
                              hipStream_t stream) {
  const float* x_seq   = (const float*)d_in[0];
  const float* x_label = (const float*)d_in[1];
  const float* W1_bel  = (const float*)d_in[2];
  const float* b1_bel  = (const float*)d_in[3];
  const float* W1_inc  = (const float*)d_in[4];
  const float* b1_inc  = (const float*)d_in[5];
  const float* W1_con  = (const float*)d_in[6];
  const float* b1_con  = (const float*)d_in[7];
  const float* g1s     = (const float*)d_in[8];
  const float* beta1s  = (const float*)d_in[9];
  const float* g1l     = (const float*)d_in[10];
  const float* beta1l  = (const float*)d_in[11];
  const float* W2_bel  = (const float*)d_in[12];
  const float* b2_bel  = (const float*)d_in[13];
  const float* W2_inc  = (const float*)d_in[14];
  const float* b2_inc  = (const float*)d_in[15];
  const float* W2_con  = (const float*)d_in[16];
  const float* b2_con  = (const float*)d_in[17];
  const float* g2s     = (const float*)d_in[18];
  const float* beta2s  = (const float*)d_in[19];
  const float* g2l     = (const float*)d_in[20];
  const float* beta2l  = (const float*)d_in[21];
  const int* bel       = (const int*)d_in[22];
  const int* con_src   = (const int*)d_in[23];
  const int* con_dst   = (const int*)d_in[24];
  float* out = (float*)d_out;

  char* ws = (char*)d_ws;
  float* bufA     = (float*)(ws);                    // 51,200,000 B
  int*   esrc     = (int*)  (ws + 51200000);         //  6,400,000 B
  // ---- zeroed region start (868,864 B) ----
  int*   deg_out  = (int*)  (ws + 57600000);
  int*   deg_in   = (int*)  (ws + 58000000);
  int*   cnt_lab  = (int*)  (ws + 58400000);
  float* lab_agg1 = (float*)(ws + 58401024);
  float* lab_agg2 = (float*)(ws + 58433792);
  float* stats1   = (float*)(ws + 58466560);
  float* stats2   = (float*)(ws + 58467584);
  int*   alloc    = (int*)  (ws + 58468608);
  // ---- zeroed region end ----
  float* dinv_out = (float*)(ws + 58468864);
  float* dinv_in  = (float*)(ws + 58868864);
  float* dinv_cnt = (float*)(ws + 59268864);
  int*   off      = (int*)  (ws + 59269120);
  int*   cursor   = (int*)  (ws + 59669120);
  float* y_inc1   = (float*)(ws + 60069120);
  float* y_inc2   = (float*)(ws + 60101888);
  float* h_l1     = (float*)(ws + 60134656);
  // end: 60,167,424 B

  // bf16 feature buffer lives in d_out[0 .. 25.6MB): holds xbf during layer 1,
  // then h1bf during layer 2; overwritten by gemm_ep2's fp32 pre-BN output.
  uint32* xb = (uint32*)out;
  // bel-pre scratch (64x128 / 64x64 fp32), in regions overwritten later:
  float* belp1 = bufA;   // con_agg1 overwrites bufA afterwards
  float* belp2 = bufA;   // con_agg2 overwrites bufA afterwards (layer 2)

  hipMemsetAsync(ws + 57600000, 0, 868864, stream);

  // degrees + CSR (shared by both layers)
  k_edge_deg  <<<(ECON + 255) / 256, 256, 0, stream>>>(con_src, con_dst, deg_out, deg_in);
  k_label_hist<<<256, 256, 0, stream>>>(bel, cnt_lab);
  k_offsets   <<<(NSEQ + 255) / 256, 256, 0, stream>>>(deg_in, deg_out, cnt_lab,
                                                       off, cursor, alloc,
                                                       dinv_out, dinv_in, dinv_cnt);
  k_scatter   <<<(ECON + 255) / 256, 256, 0, stream>>>(con_src, con_dst, cursor, esrc);
  k_cast      <<<(NSEQ * D / 4 + 255) / 256, 256, 0, stream>>>(x_seq, xb);

  // ---- layer 1 ----
  k_label_agg <<<512, 256, 0, stream>>>(xb, bel, lab_agg1);
  k_mm        <<<32, 256, 0, stream>>>(x_label, nullptr, W1_inc, nullptr, y_inc1, 128, 0);
  k_mm        <<<32, 256, 0, stream>>>(lab_agg1, dinv_cnt, W1_bel, b1_bel, belp1, 128, 1);
  k_label_bn  <<<1, 256, 0, stream>>>(belp1, g1l, beta1l, h_l1, 128);
  k_con_agg_bf<<<NSEQ / 4, 256, 0, stream>>>(xb, esrc, off, cursor,
                                             dinv_out, dinv_in, bufA);
  k_gemm_ep   <<<(NSEQ + TILE_R - 1) / TILE_R, 256, 0, stream>>>(
                  bufA, bufA, W1_con, b1_con, y_inc1, b1_inc, dinv_cnt, bel, stats1);
  k_bn_apply_cast<<<(NSEQ * D / 4 + 255) / 256, 256, 0, stream>>>(
                  bufA, stats1, g1s, beta1s, xb);   // xb now holds h1 (bf16)

  // ---- layer 2 ----
  k_label_agg <<<512, 256, 0, stream>>>(xb, bel, lab_agg2);
  k_mm        <<<32, 256, 0, stream>>>(h_l1, nullptr, W2_inc, nullptr, y_inc2, 128, 0);
  k_mm        <<<16, 256, 0, stream>>>(lab_agg2, dinv_cnt, W2_bel, b2_bel, belp2, 64, 1);
  k_label_bn  <<<1, 256, 0, stream>>>(belp2, g2l, beta2l, out + (size_t)NSEQ * D, 64);
  k_con_agg_bf<<<NSEQ / 4, 256, 0, stream>>>(xb, esrc, off, cursor,
                                             dinv_out, dinv_in, bufA);
  k_gemm_ep   <<<(NSEQ + TILE_R - 1) / TILE_R, 256, 0, stream>>>(
                  bufA, out, W2_con, b2_con, y_inc2, b2_inc, dinv_cnt, bel, stats2);
  k_bn_apply  <<<(NSEQ * D / 4 + 255) / 256, 256, 0, stream>>>(out, stats2, g2s, beta2s);
}

// Round 4
// 666.138 us; speedup vs baseline: 1.7400x; 1.2513x over previous
//
#include <hip/hip_runtime.h>
#include <hip/hip_bf16.h>

#define NSEQ 100000
#define NLAB 64
#define ECON 1600000
#define D 128
#define BN_EPS 1e-5f

#define NB 196        // dst buckets
#define BW 512        // dst per bucket (NB*BW >= NSEQ)
#define BCAP 10240    // packed-record capacity per bucket (mean 8192, >20 sigma slack)
#define EPB 4096      // edges per block in k_binA

typedef unsigned int uint32;

// ---------------- helpers ----------------
__device__ __forceinline__ void atomAddF(float* p, float v) {
  unsafeAtomicAdd(p, v);  // native global_atomic_add_f32
}
__device__ __forceinline__ float blo(uint32 u) {
  union { uint32 u; float f; } c; c.u = u << 16; return c.f;
}
__device__ __forceinline__ float bhi(uint32 u) {
  union { uint32 u; float f; } c; c.u = u & 0xFFFF0000u; return c.f;
}
__device__ __forceinline__ unsigned short f2b(float f) {
  __hip_bfloat16 h = __float2bfloat16(f);   // RNE
  union { __hip_bfloat16 h; unsigned short s; } c; c.h = h; return c.s;
}

// ---------------- label histogram ----------------
__global__ __launch_bounds__(256) void k_label_hist(const int* __restrict__ lab, int* cnt) {
  __shared__ int h[NLAB];
  if (threadIdx.x < NLAB) h[threadIdx.x] = 0;
  __syncthreads();
  for (int i = blockIdx.x * 256 + threadIdx.x; i < NSEQ; i += gridDim.x * 256)
    atomicAdd(&h[lab[i]], 1);
  __syncthreads();
  if (threadIdx.x < NLAB) atomicAdd(&cnt[threadIdx.x], h[threadIdx.x]);
}

// ---------------- CSR build pass A: bucket edges by dst ----------------------
__global__ __launch_bounds__(256) void k_binA(const int* __restrict__ src,
                                              const int* __restrict__ dst,
                                              int* deg_out, int* bucket_cnt,
                                              uint32* __restrict__ bpair) {
  __shared__ int hist[NB];
  __shared__ int base[NB];
  int t = threadIdx.x;
  for (int i = t; i < NB; i += 256) hist[i] = 0;
  __syncthreads();
  int e0 = blockIdx.x * EPB;
  int e1 = min(e0 + EPB, ECON);
  for (int e = e0 + t; e < e1; e += 256) {
    int d = dst[e];
    atomicAdd(&hist[d >> 9], 1);
    atomicAdd(&deg_out[src[e]], 1);     // global, fire-and-forget
  }
  __syncthreads();
  for (int i = t; i < NB; i += 256) {
    int c = hist[i];
    base[i] = (c > 0) ? atomicAdd(&bucket_cnt[i], c) : 0;
    hist[i] = 0;                        // reuse as local cursor
  }
  __syncthreads();
  for (int e = e0 + t; e < e1; e += 256) {   // 2nd read: L2-hot
    int d = dst[e];
    int b = d >> 9;
    int p = base[b] + atomicAdd(&hist[b], 1);
    bpair[b * BCAP + p] = (uint32)src[e] | ((uint32)(d & (BW - 1)) << 17);
  }
}

// ---------------- bucket-count scan (+ dinv_cnt) ------------------------------
__global__ __launch_bounds__(256) void k_bscan(const int* __restrict__ bucket_cnt,
                                               int* __restrict__ bbase,
                                               const int* __restrict__ cnt_lab,
                                               float* __restrict__ dinv_cnt) {
  __shared__ int s[NB];
  int t = threadIdx.x;
  if (t < NB) s[t] = bucket_cnt[t];
  __syncthreads();
  if (t == 0) {
    int acc = 0;
    for (int i = 0; i < NB; ++i) { bbase[i] = acc; acc += s[i]; }
    bbase[NB] = acc;
  }
  if (t < NLAB) { int c = cnt_lab[t]; dinv_cnt[t] = c > 0 ? rsqrtf((float)c) : 0.f; }
}

// ---------------- CSR build pass B: per-bucket scatter + node data ------------
__global__ __launch_bounds__(256) void k_binB(const uint32* __restrict__ bpair,
                                              const int* __restrict__ bucket_cnt,
                                              const int* __restrict__ bbase,
                                              const int* __restrict__ deg_out,
                                              int* __restrict__ off,
                                              float* __restrict__ dinv_in,
                                              float* __restrict__ dinv_out,
                                              int* __restrict__ esrc) {
  __shared__ int deg[BW];
  __shared__ int loff[BW];
  __shared__ int cursor[BW];
  __shared__ int wsum[4];
  int b = blockIdx.x;
  int t = threadIdx.x;
  int cnt = bucket_cnt[b];
  int gbase = bbase[b];
  const uint32* bp = &bpair[(size_t)b * BCAP];
  deg[t] = 0; deg[t + 256] = 0;
  cursor[t] = 0; cursor[t + 256] = 0;
  __syncthreads();
  for (int i = t; i < cnt; i += 256)
    atomicAdd(&deg[bp[i] >> 17], 1);
  __syncthreads();
  // exclusive scan over 512 deg values: thread t owns pair (2t, 2t+1)
  int d0 = deg[2 * t], d1 = deg[2 * t + 1];
  int ps = d0 + d1;
  int lane = t & 63, w = t >> 6;
  int v = ps;
  #pragma unroll
  for (int o = 1; o < 64; o <<= 1) { int n = __shfl_up(v, o); if (lane >= o) v += n; }
  if (lane == 63) wsum[w] = v;
  __syncthreads();
  int wbase = 0;
  for (int i = 0; i < w; ++i) wbase += wsum[i];
  int excl = wbase + v - ps;
  loff[2 * t] = excl;
  loff[2 * t + 1] = excl + d0;
  __syncthreads();
  // node-ordered CSR offsets + dinv (coalesced writes)
  #pragma unroll
  for (int k = 0; k < 2; ++k) {
    int j = t + k * 256;
    int node = b * BW + j;
    if (node < NSEQ) {
      int dg = deg[j];
      off[node] = gbase + loff[j];
      dinv_in[node] = dg > 0 ? rsqrtf((float)dg) : 0.f;
      int dgo = deg_out[node];
      dinv_out[node] = dgo > 0 ? rsqrtf((float)dgo) : 0.f;
    }
  }
  if (b == NB - 1 && t == 0) off[NSEQ] = ECON;
  // scatter into the bucket's contiguous esrc window (~32 KB)
  for (int i = t; i < cnt; i += 256) {
    uint32 pk = bp[i];
    int dl = pk >> 17;
    int p = gbase + loff[dl] + atomicAdd(&cursor[dl], 1);
    esrc[p] = (int)(pk & 0x1FFFF);
  }
}

// ---------------- fp32 -> bf16 cast -------------------------------------------
__global__ __launch_bounds__(256) void k_cast(const float* __restrict__ x,
                                              uint32* __restrict__ xb) {
  int i = blockIdx.x * 256 + threadIdx.x;     // float4 index
  if (i >= NSEQ * D / 4) return;
  float4 v = ((const float4*)x)[i];
  uint32 u0 = (uint32)f2b(v.x) | ((uint32)f2b(v.y) << 16);
  uint32 u1 = (uint32)f2b(v.z) | ((uint32)f2b(v.w) << 16);
  ((uint2*)xb)[i] = make_uint2(u0, u1);
}

// ---------------- label aggregation from bf16 ---------------------------------
__global__ __launch_bounds__(256) void k_label_agg(const uint32* __restrict__ xb,
                                                   const int* __restrict__ lab,
                                                   float* lab_agg) {
  __shared__ float acc[NLAB * D];   // 32 KB
  for (int i = threadIdx.x; i < NLAB * D; i += 256) acc[i] = 0.f;
  __syncthreads();
  int cp = threadIdx.x & 63;        // col pair
  int rsub = threadIdx.x >> 6;      // 0..3
  for (int r = blockIdx.x * 4 + rsub; r < NSEQ; r += gridDim.x * 4) {
    int l = lab[r];
    uint32 u = xb[r * 64 + cp];
    atomicAdd(&acc[l * D + 2 * cp], blo(u));
    atomicAdd(&acc[l * D + 2 * cp + 1], bhi(u));
  }
  __syncthreads();
  for (int i = threadIdx.x; i < NLAB * D; i += 256) atomAddF(&lab_agg[i], acc[i]);
}

// ---------------- small matmul: out[64][ncol] = op((A*rowscale) @ W + bias) ---
__global__ __launch_bounds__(256) void k_mm(
    const float* __restrict__ A,        // 64 x 128
    const float* __restrict__ rowscale, // 64 (or nullptr)
    const float* __restrict__ W,        // 128 x ncol
    const float* __restrict__ bias,     // ncol (or nullptr)
    float* __restrict__ out,            // 64 x ncol
    int ncol, int relu) {
  __shared__ float sA[4 * D];
  int tid = threadIdx.x;
  int rows_pb = 256 / ncol;
  int row0 = blockIdx.x * rows_pb;
  int nload = rows_pb * D;
  for (int i = tid; i < nload; i += 256) {
    int r = row0 + (i >> 7);
    float s = rowscale ? rowscale[r] : 1.f;
    sA[i] = A[r * D + (i & 127)] * s;
  }
  __syncthreads();
  int j = tid & (ncol - 1);
  int r = tid / ncol;
  const float* a = &sA[r * D];
  const float* w = &W[j];
  float acc0 = 0.f, acc1 = 0.f, acc2 = 0.f, acc3 = 0.f;
  #pragma unroll 4
  for (int k = 0; k < D; k += 4) {
    acc0 = fmaf(a[k + 0], w[(k + 0) * ncol], acc0);
    acc1 = fmaf(a[k + 1], w[(k + 1) * ncol], acc1);
    acc2 = fmaf(a[k + 2], w[(k + 2) * ncol], acc2);
    acc3 = fmaf(a[k + 3], w[(k + 3) * ncol], acc3);
  }
  float s = (acc0 + acc1) + (acc2 + acc3);
  if (bias) s += bias[j];
  if (relu) s = fmaxf(s, 0.f);
  out[(row0 + r) * ncol + j] = s;
}

// ---------------- BN over 64 label rows ---------------------------------------
__global__ __launch_bounds__(256) void k_label_bn(
    const float* __restrict__ pre,   // 64 x ncol
    const float* __restrict__ g, const float* __restrict__ beta,
    float* __restrict__ out,         // 64 x ncol
    int ncol) {
  __shared__ float psum[256], psq[256];
  __shared__ float sa[128], sc[128];
  int tid = threadIdx.x;
  int ngrp = 256 / ncol;
  int grp = tid / ncol;
  int col = tid & (ncol - 1);
  float s = 0.f, q = 0.f;
  for (int r = grp; r < NLAB; r += ngrp) {
    float v = pre[r * ncol + col];
    s += v; q += v * v;
  }
  psum[tid] = s; psq[tid] = q;
  __syncthreads();
  if (tid < ncol) {
    float S = 0.f, Q = 0.f;
    for (int gi = 0; gi < ngrp; ++gi) { S += psum[gi * ncol + tid]; Q += psq[gi * ncol + tid]; }
    float m = S * (1.f / NLAB);
    float v = Q * (1.f / NLAB) - m * m;
    float a = rsqrtf(v + BN_EPS) * g[tid];
    sa[tid] = a; sc[tid] = beta[tid] - m * a;
  }
  __syncthreads();
  for (int i = tid; i < NLAB * ncol; i += 256) {
    int c = i & (ncol - 1);
    out[i] = pre[i] * sa[c] + sc[c];
  }
}

// ---------------- connected_to aggregation from bf16: one wave per dst row ----
__global__ __launch_bounds__(256) void k_con_agg_bf(
    const uint32* __restrict__ xb, const int* __restrict__ esrc,
    const int* __restrict__ off,
    const float* __restrict__ dinv_out, const float* __restrict__ dinv_in,
    float* __restrict__ out) {
  int wid = (blockIdx.x * 256 + threadIdx.x) >> 6;   // dst node
  int lane = threadIdx.x & 63;
  if (wid >= NSEQ) return;
  int e0 = off[wid], e1 = off[wid + 1];
  float ax = 0.f, ay = 0.f;
  int e = e0;
  for (; e + 3 < e1; e += 4) {      // 4-edge unroll for load ILP
    int s0 = esrc[e], s1 = esrc[e + 1], s2 = esrc[e + 2], s3 = esrc[e + 3];
    float w0 = dinv_out[s0], w1 = dinv_out[s1], w2 = dinv_out[s2], w3 = dinv_out[s3];
    uint32 u0 = xb[s0 * 64 + lane];
    uint32 u1 = xb[s1 * 64 + lane];
    uint32 u2 = xb[s2 * 64 + lane];
    uint32 u3 = xb[s3 * 64 + lane];
    ax += blo(u0) * w0 + blo(u1) * w1 + blo(u2) * w2 + blo(u3) * w3;
    ay += bhi(u0) * w0 + bhi(u1) * w1 + bhi(u2) * w2 + bhi(u3) * w3;
  }
  for (; e < e1; ++e) {
    int s0 = esrc[e];
    float w0 = dinv_out[s0];
    uint32 u0 = xb[s0 * 64 + lane];
    ax += blo(u0) * w0;
    ay += bhi(u0) * w0;
  }
  float di = dinv_in[wid];
  float2 o; o.x = ax * di; o.y = ay * di;
  ((float2*)out)[wid * 64 + lane] = o;
}

// ---------------- GEMM + epilogue + BN stats ----------------------------------
#define TILE_R 64
__global__ __launch_bounds__(256) void k_gemm_ep(
    const float* __restrict__ bufIn,   // NSEQ x 128 (agg)
    float* __restrict__ bufOut,        // NSEQ x 128 (pre-BN h, may alias bufIn)
    const float* __restrict__ W,       // 128x128
    const float* __restrict__ b_con,   // 128
    const float* __restrict__ y_inc,   // 64x128
    const float* __restrict__ b_inc,   // 128
    const float* __restrict__ dinv_cnt,
    const int* __restrict__ bel,
    float* __restrict__ stats) {       // [sum 128][sumsq 128]
  __shared__ float sA[TILE_R][D];      // 32 KB
  __shared__ float csum[D], csq[D];
  int tid = threadIdx.x;
  int row0 = blockIdx.x * TILE_R;
  for (int i = tid; i < TILE_R * D / 4; i += 256) {
    int r = i >> 5;
    int c = (i & 31) * 4;
    int row = row0 + r;
    float4 v = make_float4(0.f, 0.f, 0.f, 0.f);
    if (row < NSEQ) v = *(const float4*)&bufIn[row * D + c];
    *(float4*)&sA[r][c] = v;
  }
  if (tid < D) { csum[tid] = 0.f; csq[tid] = 0.f; }
  __syncthreads();

  int tx = tid & 31, ty = tid >> 5;
  int c0 = tx * 4, r0 = ty * 8;
  float acc[8][4];
  #pragma unroll
  for (int i = 0; i < 8; i++)
    #pragma unroll
    for (int j = 0; j < 4; j++) acc[i][j] = 0.f;

  for (int k = 0; k < D; k += 4) {
    float4 w0 = *(const float4*)&W[(k + 0) * D + c0];
    float4 w1 = *(const float4*)&W[(k + 1) * D + c0];
    float4 w2 = *(const float4*)&W[(k + 2) * D + c0];
    float4 w3 = *(const float4*)&W[(k + 3) * D + c0];
    #pragma unroll
    for (int i = 0; i < 8; i++) {
      float4 a = *(const float4*)&sA[r0 + i][k];   // ds_read_b128
      acc[i][0] = fmaf(a.x, w0.x, acc[i][0]);
      acc[i][1] = fmaf(a.x, w0.y, acc[i][1]);
      acc[i][2] = fmaf(a.x, w0.z, acc[i][2]);
      acc[i][3] = fmaf(a.x, w0.w, acc[i][3]);
      acc[i][0] = fmaf(a.y, w1.x, acc[i][0]);
      acc[i][1] = fmaf(a.y, w1.y, acc[i][1]);
      acc[i][2] = fmaf(a.y, w1.z, acc[i][2]);
      acc[i][3] = fmaf(a.y, w1.w, acc[i][3]);
      acc[i][0] = fmaf(a.z, w2.x, acc[i][0]);
      acc[i][1] = fmaf(a.z, w2.y, acc[i][1]);
      acc[i][2] = fmaf(a.z, w2.z, acc[i][2]);
      acc[i][3] = fmaf(a.z, w2.w, acc[i][3]);
      acc[i][0] = fmaf(a.w, w3.x, acc[i][0]);
      acc[i][1] = fmaf(a.w, w3.y, acc[i][1]);
      acc[i][2] = fmaf(a.w, w3.z, acc[i][2]);
      acc[i][3] = fmaf(a.w, w3.w, acc[i][3]);
    }
  }

  float4 bcn = *(const float4*)&b_con[c0];
  float4 bic = *(const float4*)&b_inc[c0];
  float ps[4] = {0.f, 0.f, 0.f, 0.f}, pq[4] = {0.f, 0.f, 0.f, 0.f};
  #pragma unroll
  for (int i = 0; i < 8; i++) {
    int row = row0 + r0 + i;
    if (row < NSEQ) {
      int l = bel[row];
      float dc = dinv_cnt[l];
      float4 yi = *(const float4*)&y_inc[l * D + c0];
      float o0 = fmaxf(0.5f * (acc[i][0] + bcn.x + fmaf(dc, yi.x, bic.x)), 0.f);
      float o1 = fmaxf(0.5f * (acc[i][1] + bcn.y + fmaf(dc, yi.y, bic.y)), 0.f);
      float o2 = fmaxf(0.5f * (acc[i][2] + bcn.z + fmaf(dc, yi.z, bic.z)), 0.f);
      float o3 = fmaxf(0.5f * (acc[i][3] + bcn.w + fmaf(dc, yi.w, bic.w)), 0.f);
      *(float4*)&bufOut[row * D + c0] = make_float4(o0, o1, o2, o3);
      ps[0] += o0; ps[1] += o1; ps[2] += o2; ps[3] += o3;
      pq[0] += o0 * o0; pq[1] += o1 * o1; pq[2] += o2 * o2; pq[3] += o3 * o3;
    }
  }
  #pragma unroll
  for (int j = 0; j < 4; j++) {
    atomicAdd(&csum[c0 + j], ps[j]);
    atomicAdd(&csq[c0 + j], pq[j]);
  }
  __syncthreads();
  if (tid < D) {
    atomAddF(&stats[tid], csum[tid]);
    atomAddF(&stats[D + tid], csq[tid]);
  }
}

// ---------------- BN apply + cast to bf16 (layer 1) ---------------------------
__global__ __launch_bounds__(256) void k_bn_apply_cast(
    const float* __restrict__ buf, const float* __restrict__ stats,
    const float* __restrict__ g, const float* __restrict__ beta,
    uint32* __restrict__ xb) {
  int i = blockIdx.x * 256 + threadIdx.x;     // float4 index
  if (i >= NSEQ * D / 4) return;
  int c = (i * 4) & (D - 1);
  float4 v = ((const float4*)buf)[i];
  float4 s = *(const float4*)&stats[c];
  float4 q = *(const float4*)&stats[D + c];
  float4 gg = *(const float4*)&g[c];
  float4 bb = *(const float4*)&beta[c];
  const float invN = 1.f / (float)NSEQ;
  float m, var, a;
  m = s.x * invN; var = q.x * invN - m * m; a = rsqrtf(var + BN_EPS) * gg.x; v.x = (v.x - m) * a + bb.x;
  m = s.y * invN; var = q.y * invN - m * m; a = rsqrtf(var + BN_EPS) * gg.y; v.y = (v.y - m) * a + bb.y;
  m = s.z * invN; var = q.z * invN - m * m; a = rsqrtf(var + BN_EPS) * gg.z; v.z = (v.z - m) * a + bb.z;
  m = s.w * invN; var = q.w * invN - m * m; a = rsqrtf(var + BN_EPS) * gg.w; v.w = (v.w - m) * a + bb.w;
  uint32 u0 = (uint32)f2b(v.x) | ((uint32)f2b(v.y) << 16);
  uint32 u1 = (uint32)f2b(v.z) | ((uint32)f2b(v.w) << 16);
  ((uint2*)xb)[i] = make_uint2(u0, u1);
}

// ---------------- BN apply (final, fp32 in place) ------------------------------
__global__ __launch_bounds__(256) void k_bn_apply(float* __restrict__ buf,
                                                  const float* __restrict__ stats,
                                                  const float* __restrict__ g,
                                                  const float* __restrict__ beta) {
  int i = blockIdx.x * 256 + threadIdx.x;     // float4 index
  if (i >= NSEQ * D / 4) return;
  int c = (i * 4) & (D - 1);
  float4 v = ((float4*)buf)[i];
  float4 s = *(const float4*)&stats[c];
  float4 q = *(const float4*)&stats[D + c];
  float4 gg = *(const float4*)&g[c];
  float4 bb = *(const float4*)&beta[c];
  const float invN = 1.f / (float)NSEQ;
  float m, var, a;
  m = s.x * invN; var = q.x * invN - m * m; a = rsqrtf(var + BN_EPS) * gg.x; v.x = (v.x - m) * a + bb.x;
  m = s.y * invN; var = q.y * invN - m * m; a = rsqrtf(var + BN_EPS) * gg.y; v.y = (v.y - m) * a + bb.y;
  m = s.z * invN; var = q.z * invN - m * m; a = rsqrtf(var + BN_EPS) * gg.z; v.z = (v.z - m) * a + bb.z;
  m = s.w * invN; var = q.w * invN - m * m; a = rsqrtf(var + BN_EPS) * gg.w; v.w = (v.w - m) * a + bb.w;
  ((float4*)buf)[i] = v;
}

// ---------------- launch ------------------------------------------------------
extern "C" void kernel_launch(void* const* d_in, const int* in_sizes, int n_in,
                              void* d_out, int out_size, void* d_ws, size_t ws_size,
                              hipStream_t stream) {
  const float* x_seq   = (const float*)d_in[0];
  const float* x_label = (const float*)d_in[1];
  const float* W1_bel  = (const float*)d_in[2];
  const float* b1_bel  = (const float*)d_in[3];
  const float* W1_inc  = (const float*)d_in[4];
  const float* b1_inc  = (const float*)d_in[5];
  const float* W1_con  = (const float*)d_in[6];
  const float* b1_con  = (const float*)d_in[7];
  const float* g1s     = (const float*)d_in[8];
  const float* beta1s  = (const float*)d_in[9];
  const float* g1l     = (const float*)d_in[10];
  const float* beta1l  = (const float*)d_in[11];
  const float* W2_bel  = (const float*)d_in[12];
  const float* b2_bel  = (const float*)d_in[13];
  const float* W2_inc  = (const float*)d_in[14];
  const float* b2_inc  = (const float*)d_in[15];
  const float* W2_con  = (const float*)d_in[16];
  const float* b2_con  = (const float*)d_in[17];
  const float* g2s     = (const float*)d_in[18];
  const float* beta2s  = (const float*)d_in[19];
  const float* g2l     = (const float*)d_in[20];
  const float* beta2l  = (const float*)d_in[21];
  const int* bel       = (const int*)d_in[22];
  const int* con_src   = (const int*)d_in[23];
  const int* con_dst   = (const int*)d_in[24];
  float* out = (float*)d_out;

  char* ws = (char*)d_ws;
  float*  bufA     = (float*) (ws);                  // 51,200,000 B
  uint32* bpair    = (uint32*)(ws + 32000000);       //  8,028,160 B (transient, inside bufA)
  int*    esrc     = (int*)   (ws + 51200000);       //  6,400,000 B
  // ---- zeroed region start (469,632 B) ----
  int*    deg_out    = (int*)  (ws + 57600000);      // 400,000
  int*    cnt_lab    = (int*)  (ws + 58000000);      //   1,024
  int*    bucket_cnt = (int*)  (ws + 58001024);      //   1,024 (196 used)
  float*  lab_agg1   = (float*)(ws + 58002048);      //  32,768
  float*  lab_agg2   = (float*)(ws + 58034816);      //  32,768
  float*  stats1     = (float*)(ws + 58067584);      //   1,024
  float*  stats2     = (float*)(ws + 58068608);      //   1,024
  // ---- zeroed region end (58,069,632) ----
  float*  dinv_out = (float*)(ws + 58069632);        // 400,000
  float*  dinv_in  = (float*)(ws + 58469632);        // 400,000
  float*  dinv_cnt = (float*)(ws + 58869632);        //     256
  int*    bbase    = (int*)  (ws + 58869888);        //   1,024 (197 used)
  int*    off      = (int*)  (ws + 58870912);        // 400,128 (NSEQ+1 ints)
  float*  y_inc1   = (float*)(ws + 59271040);        //  32,768
  float*  y_inc2   = (float*)(ws + 59303808);        //  32,768
  float*  h_l1     = (float*)(ws + 59336576);        //  32,768
  // end: 59,369,344 B

  // bf16 feature buffer lives in d_out[0 .. 25.6MB): xbf in layer 1, h1bf in
  // layer 2; overwritten by gemm_ep2's fp32 output.
  uint32* xb = (uint32*)out;
  // bel-pre scratch (<=64x128 fp32) at front of bufA (no overlap with bpair):
  float* belp1 = bufA;
  float* belp2 = bufA;

  hipMemsetAsync(ws + 57600000, 0, 469632, stream);

  // CSR build (bucketed counting sort) + degrees
  k_label_hist<<<256, 256, 0, stream>>>(bel, cnt_lab);
  k_binA      <<<(ECON + EPB - 1) / EPB, 256, 0, stream>>>(con_src, con_dst,
                                                           deg_out, bucket_cnt, bpair);
  k_bscan     <<<1, 256, 0, stream>>>(bucket_cnt, bbase, cnt_lab, dinv_cnt);
  k_binB      <<<NB, 256, 0, stream>>>(bpair, bucket_cnt, bbase, deg_out,
                                       off, dinv_in, dinv_out, esrc);
  k_cast      <<<(NSEQ * D / 4 + 255) / 256, 256, 0, stream>>>(x_seq, xb);

  // ---- layer 1 ----
  k_label_agg <<<512, 256, 0, stream>>>(xb, bel, lab_agg1);
  k_mm        <<<32, 256, 0, stream>>>(x_label, nullptr, W1_inc, nullptr, y_inc1, 128, 0);
  k_mm        <<<32, 256, 0, stream>>>(lab_agg1, dinv_cnt, W1_bel, b1_bel, belp1, 128, 1);
  k_label_bn  <<<1, 256, 0, stream>>>(belp1, g1l, beta1l, h_l1, 128);
  k_con_agg_bf<<<NSEQ / 4, 256, 0, stream>>>(xb, esrc, off, dinv_out, dinv_in, bufA);
  k_gemm_ep   <<<(NSEQ + TILE_R - 1) / TILE_R, 256, 0, stream>>>(
                  bufA, bufA, W1_con, b1_con, y_inc1, b1_inc, dinv_cnt, bel, stats1);
  k_bn_apply_cast<<<(NSEQ * D / 4 + 255) / 256, 256, 0, stream>>>(
                  bufA, stats1, g1s, beta1s, xb);   // xb now holds h1 (bf16)

  // ---- layer 2 ----
  k_label_agg <<<512, 256, 0, stream>>>(xb, bel, lab_agg2);
  k_mm        <<<32, 256, 0, stream>>>(h_l1, nullptr, W2_inc, nullptr, y_inc2, 128, 0);
  k_mm        <<<16, 256, 0, stream>>>(lab_agg2, dinv_cnt, W2_bel, b2_bel, belp2, 64, 1);
  k_label_bn  <<<1, 256, 0, stream>>>(belp2, g2l, beta2l, out + (size_t)NSEQ * D, 64);
  k_con_agg_bf<<<NSEQ / 4, 256, 0, stream>>>(xb, esrc, off, dinv_out, dinv_in, bufA);
  k_gemm_ep   <<<(NSEQ + TILE_R - 1) / TILE_R, 256, 0, stream>>>(
                  bufA, out, W2_con, b2_con, y_inc2, b2_inc, dinv_cnt, bel, stats2);
  k_bn_apply  <<<(NSEQ * D / 4 + 255) / 256, 256, 0, stream>>>(out, stats2, g2s, beta2s);
}

// Round 6
// 614.171 us; speedup vs baseline: 1.8873x; 1.0846x over previous
//
#include <hip/hip_runtime.h>
#include <hip/hip_bf16.h>

#define NSEQ 100000
#define NLAB 64
#define ECON 1600000
#define D 128
#define BN_EPS 1e-5f

#define NB 196        // dst buckets
#define BW 512        // dst per bucket (NB*BW >= NSEQ)
#define BCAP 10240    // packed-record capacity per bucket
#define EPB 4096      // edges per block in k_binA

typedef unsigned int uint32;
typedef __attribute__((ext_vector_type(8))) short bf16x8;
typedef __attribute__((ext_vector_type(4))) float f32x4;

// ---------------- helpers ----------------
__device__ __forceinline__ void atomAddF(float* p, float v) {
  unsafeAtomicAdd(p, v);  // native global_atomic_add_f32
}
__device__ __forceinline__ float blo(uint32 u) {
  union { uint32 u; float f; } c; c.u = u << 16; return c.f;
}
__device__ __forceinline__ float bhi(uint32 u) {
  union { uint32 u; float f; } c; c.u = u & 0xFFFF0000u; return c.f;
}
__device__ __forceinline__ unsigned short f2b(float f) {
  __hip_bfloat16 h = __float2bfloat16(f);   // RNE
  union { __hip_bfloat16 h; unsigned short s; } c; c.h = h; return c.s;
}

// ---------------- label histogram ----------------
__global__ __launch_bounds__(256) void k_label_hist(const int* __restrict__ lab, int* cnt) {
  __shared__ int h[NLAB];
  if (threadIdx.x < NLAB) h[threadIdx.x] = 0;
  __syncthreads();
  for (int i = blockIdx.x * 256 + threadIdx.x; i < NSEQ; i += gridDim.x * 256)
    atomicAdd(&h[lab[i]], 1);
  __syncthreads();
  if (threadIdx.x < NLAB) atomicAdd(&cnt[threadIdx.x], h[threadIdx.x]);
}

// ---------------- CSR build pass A: bucket edges by dst ----------------------
__global__ __launch_bounds__(256) void k_binA(const int* __restrict__ src,
                                              const int* __restrict__ dst,
                                              int* deg_out, int* bucket_cnt,
                                              uint32* __restrict__ bpair) {
  __shared__ int hist[NB];
  __shared__ int base[NB];
  int t = threadIdx.x;
  for (int i = t; i < NB; i += 256) hist[i] = 0;
  __syncthreads();
  int e0 = blockIdx.x * EPB;
  int e1 = min(e0 + EPB, ECON);
  for (int e = e0 + t; e < e1; e += 256) {
    int d = dst[e];
    atomicAdd(&hist[d >> 9], 1);
    atomicAdd(&deg_out[src[e]], 1);     // global, fire-and-forget
  }
  __syncthreads();
  for (int i = t; i < NB; i += 256) {
    int c = hist[i];
    base[i] = (c > 0) ? atomicAdd(&bucket_cnt[i], c) : 0;
    hist[i] = 0;                        // reuse as local cursor
  }
  __syncthreads();
  for (int e = e0 + t; e < e1; e += 256) {   // 2nd read: L2-hot
    int d = dst[e];
    int b = d >> 9;
    int p = base[b] + atomicAdd(&hist[b], 1);
    bpair[b * BCAP + p] = (uint32)src[e] | ((uint32)(d & (BW - 1)) << 17);
  }
}

// ---------------- bucket-count scan (+ dinv_cnt) ------------------------------
__global__ __launch_bounds__(256) void k_bscan(const int* __restrict__ bucket_cnt,
                                               int* __restrict__ bbase,
                                               const int* __restrict__ cnt_lab,
                                               float* __restrict__ dinv_cnt) {
  __shared__ int s[NB];
  int t = threadIdx.x;
  if (t < NB) s[t] = bucket_cnt[t];
  __syncthreads();
  if (t == 0) {
    int acc = 0;
    for (int i = 0; i < NB; ++i) { bbase[i] = acc; acc += s[i]; }
    bbase[NB] = acc;
  }
  if (t < NLAB) { int c = cnt_lab[t]; dinv_cnt[t] = c > 0 ? rsqrtf((float)c) : 0.f; }
}

// ---------------- CSR build pass B: per-bucket scatter + node data ------------
__global__ __launch_bounds__(256) void k_binB(const uint32* __restrict__ bpair,
                                              const int* __restrict__ bucket_cnt,
                                              const int* __restrict__ bbase,
                                              const int* __restrict__ deg_out,
                                              int* __restrict__ off,
                                              float* __restrict__ dinv_in,
                                              float* __restrict__ dinv_out,
                                              int* __restrict__ esrc) {
  __shared__ int deg[BW];
  __shared__ int loff[BW];
  __shared__ int cursor[BW];
  __shared__ int wsum[4];
  int b = blockIdx.x;
  int t = threadIdx.x;
  int cnt = bucket_cnt[b];
  int gbase = bbase[b];
  const uint32* bp = &bpair[(size_t)b * BCAP];
  deg[t] = 0; deg[t + 256] = 0;
  cursor[t] = 0; cursor[t + 256] = 0;
  __syncthreads();
  for (int i = t; i < cnt; i += 256)
    atomicAdd(&deg[bp[i] >> 17], 1);
  __syncthreads();
  int d0 = deg[2 * t], d1 = deg[2 * t + 1];
  int ps = d0 + d1;
  int lane = t & 63, w = t >> 6;
  int v = ps;
  #pragma unroll
  for (int o = 1; o < 64; o <<= 1) { int n = __shfl_up(v, o); if (lane >= o) v += n; }
  if (lane == 63) wsum[w] = v;
  __syncthreads();
  int wbase = 0;
  for (int i = 0; i < w; ++i) wbase += wsum[i];
  int excl = wbase + v - ps;
  loff[2 * t] = excl;
  loff[2 * t + 1] = excl + d0;
  __syncthreads();
  #pragma unroll
  for (int k = 0; k < 2; ++k) {
    int j = t + k * 256;
    int node = b * BW + j;
    if (node < NSEQ) {
      int dg = deg[j];
      off[node] = gbase + loff[j];
      dinv_in[node] = dg > 0 ? rsqrtf((float)dg) : 0.f;
      int dgo = deg_out[node];
      dinv_out[node] = dgo > 0 ? rsqrtf((float)dgo) : 0.f;
    }
  }
  if (b == NB - 1 && t == 0) off[NSEQ] = ECON;
  for (int i = t; i < cnt; i += 256) {
    uint32 pk = bp[i];
    int dl = pk >> 17;
    int p = gbase + loff[dl] + atomicAdd(&cursor[dl], 1);
    esrc[p] = (int)(pk & 0x1FFFF);
  }
}

// ---------------- fp32 -> bf16 cast -------------------------------------------
__global__ __launch_bounds__(256) void k_cast(const float* __restrict__ x,
                                              uint32* __restrict__ xb) {
  int i = blockIdx.x * 256 + threadIdx.x;     // float4 index
  if (i >= NSEQ * D / 4) return;
  float4 v = ((const float4*)x)[i];
  uint32 u0 = (uint32)f2b(v.x) | ((uint32)f2b(v.y) << 16);
  uint32 u1 = (uint32)f2b(v.z) | ((uint32)f2b(v.w) << 16);
  ((uint2*)xb)[i] = make_uint2(u0, u1);
}

// ---------------- weight prep: W (128x128 fp32, k-major) -> W^T bf16 ----------
__global__ __launch_bounds__(256) void k_prep_w(const float* __restrict__ W1,
                                                const float* __restrict__ W2,
                                                short* __restrict__ wT1,
                                                short* __restrict__ wT2) {
  int i = blockIdx.x * 256 + threadIdx.x;
  if (i < 16384) {
    int k = i >> 7, c = i & 127;
    wT1[c * 128 + k] = (short)f2b(W1[i]);
  } else if (i < 32768) {
    int j = i - 16384;
    int k = j >> 7, c = j & 127;
    wT2[c * 128 + k] = (short)f2b(W2[j]);
  }
}

// ---------------- label aggregation from bf16 ---------------------------------
__global__ __launch_bounds__(256) void k_label_agg(const uint32* __restrict__ xb,
                                                   const int* __restrict__ lab,
                                                   float* lab_agg) {
  __shared__ float acc[NLAB * D];   // 32 KB
  for (int i = threadIdx.x; i < NLAB * D; i += 256) acc[i] = 0.f;
  __syncthreads();
  int cp = threadIdx.x & 63;
  int rsub = threadIdx.x >> 6;
  for (int r = blockIdx.x * 4 + rsub; r < NSEQ; r += gridDim.x * 4) {
    int l = lab[r];
    uint32 u = xb[r * 64 + cp];
    atomicAdd(&acc[l * D + 2 * cp], blo(u));
    atomicAdd(&acc[l * D + 2 * cp + 1], bhi(u));
  }
  __syncthreads();
  for (int i = threadIdx.x; i < NLAB * D; i += 256) atomAddF(&lab_agg[i], acc[i]);
}

// ---------------- small matmul: out[64][ncol] = op((A*rowscale) @ W + bias) ---
__global__ __launch_bounds__(256) void k_mm(
    const float* __restrict__ A, const float* __restrict__ rowscale,
    const float* __restrict__ W, const float* __restrict__ bias,
    float* __restrict__ out, int ncol, int relu) {
  __shared__ float sA[4 * D];
  int tid = threadIdx.x;
  int rows_pb = 256 / ncol;
  int row0 = blockIdx.x * rows_pb;
  int nload = rows_pb * D;
  for (int i = tid; i < nload; i += 256) {
    int r = row0 + (i >> 7);
    float s = rowscale ? rowscale[r] : 1.f;
    sA[i] = A[r * D + (i & 127)] * s;
  }
  __syncthreads();
  int j = tid & (ncol - 1);
  int r = tid / ncol;
  const float* a = &sA[r * D];
  const float* w = &W[j];
  float acc0 = 0.f, acc1 = 0.f, acc2 = 0.f, acc3 = 0.f;
  #pragma unroll 4
  for (int k = 0; k < D; k += 4) {
    acc0 = fmaf(a[k + 0], w[(k + 0) * ncol], acc0);
    acc1 = fmaf(a[k + 1], w[(k + 1) * ncol], acc1);
    acc2 = fmaf(a[k + 2], w[(k + 2) * ncol], acc2);
    acc3 = fmaf(a[k + 3], w[(k + 3) * ncol], acc3);
  }
  float s = (acc0 + acc1) + (acc2 + acc3);
  if (bias) s += bias[j];
  if (relu) s = fmaxf(s, 0.f);
  out[(row0 + r) * ncol + j] = s;
}

// ---------------- BN over 64 label rows ---------------------------------------
__global__ __launch_bounds__(256) void k_label_bn(
    const float* __restrict__ pre,
    const float* __restrict__ g, const float* __restrict__ beta,
    float* __restrict__ out, int ncol) {
  __shared__ float psum[256], psq[256];
  __shared__ float sa[128], sc[128];
  int tid = threadIdx.x;
  int ngrp = 256 / ncol;
  int grp = tid / ncol;
  int col = tid & (ncol - 1);
  float s = 0.f, q = 0.f;
  for (int r = grp; r < NLAB; r += ngrp) {
    float v = pre[r * ncol + col];
    s += v; q += v * v;
  }
  psum[tid] = s; psq[tid] = q;
  __syncthreads();
  if (tid < ncol) {
    float S = 0.f, Q = 0.f;
    for (int gi = 0; gi < ngrp; ++gi) { S += psum[gi * ncol + tid]; Q += psq[gi * ncol + tid]; }
    float m = S * (1.f / NLAB);
    float v = Q * (1.f / NLAB) - m * m;
    float a = rsqrtf(v + BN_EPS) * g[tid];
    sa[tid] = a; sc[tid] = beta[tid] - m * a;
  }
  __syncthreads();
  for (int i = tid; i < NLAB * ncol; i += 256) {
    int c = i & (ncol - 1);
    out[i] = pre[i] * sa[c] + sc[c];
  }
}

// ---------------- connected_to aggregation: bf16 in, bf16 out -----------------
__global__ __launch_bounds__(256) void k_con_agg_bf(
    const uint32* __restrict__ xb, const int* __restrict__ esrc,
    const int* __restrict__ off,
    const float* __restrict__ dinv_out, const float* __restrict__ dinv_in,
    uint32* __restrict__ outb) {
  int wid = (blockIdx.x * 256 + threadIdx.x) >> 6;   // dst node
  int lane = threadIdx.x & 63;
  if (wid >= NSEQ) return;
  int e0 = off[wid], e1 = off[wid + 1];
  float ax = 0.f, ay = 0.f;
  int e = e0;
  for (; e + 3 < e1; e += 4) {
    int s0 = esrc[e], s1 = esrc[e + 1], s2 = esrc[e + 2], s3 = esrc[e + 3];
    float w0 = dinv_out[s0], w1 = dinv_out[s1], w2 = dinv_out[s2], w3 = dinv_out[s3];
    uint32 u0 = xb[s0 * 64 + lane];
    uint32 u1 = xb[s1 * 64 + lane];
    uint32 u2 = xb[s2 * 64 + lane];
    uint32 u3 = xb[s3 * 64 + lane];
    ax += blo(u0) * w0 + blo(u1) * w1 + blo(u2) * w2 + blo(u3) * w3;
    ay += bhi(u0) * w0 + bhi(u1) * w1 + bhi(u2) * w2 + bhi(u3) * w3;
  }
  for (; e < e1; ++e) {
    int s0 = esrc[e];
    float w0 = dinv_out[s0];
    uint32 u0 = xb[s0 * 64 + lane];
    ax += blo(u0) * w0;
    ay += bhi(u0) * w0;
  }
  float di = dinv_in[wid];
  uint32 p = (uint32)f2b(ax * di) | ((uint32)f2b(ay * di) << 16);
  outb[wid * 64 + lane] = p;
}

// ---------------- MFMA GEMM + epilogue + BN stats ------------------------------
// block = 64 rows (4 waves x 16), cols = 128. A: bf16 global. W^T: bf16 -> LDS.
template <int OUTBF>
__global__ __launch_bounds__(256) void k_gemm_mfma(
    const short* __restrict__ aggbf,    // NSEQ x 128 bf16
    const short* __restrict__ wT,       // 128(col) x 128(k) bf16
    const float* __restrict__ b_con,
    const float* __restrict__ y_inc,    // 64x128 fp32
    const float* __restrict__ b_inc,
    const float* __restrict__ dinv_cnt,
    const int* __restrict__ bel,
    float* __restrict__ outF,           // fp32 out (OUTBF=0)
    short* __restrict__ outB,           // bf16 out (OUTBF=1)
    float* __restrict__ stats) {
  __shared__ short sW[128 * 136];       // 272B row stride: bank-safe ds_read_b128
  __shared__ float csum[D], csq[D];
  int t = threadIdx.x;
  {
    // wT = 128 rows x 128 shorts = 2048 uint4 (16 uint4 per row).
    // sW row stride = 136 shorts; one uint4 = 8 shorts.
    const uint4* src = (const uint4*)wT;
    for (int i = t; i < 2048; i += 256) {
      int row = i >> 4, part = i & 15;
      *(uint4*)&sW[row * 136 + part * 8] = src[i];
    }
  }
  if (t < D) { csum[t] = 0.f; csq[t] = 0.f; }
  int w = t >> 6, l = t & 63;
  int lr = l & 15, lg = l >> 4;
  int row0 = blockIdx.x * 64 + w * 16;
  // A fragments: 16 rows x 128 k per wave; lane holds row (lr), k = kt*32+lg*8..+8
  bf16x8 afrag[4];
  {
    int arow = min(row0 + lr, NSEQ - 1);
    const short* ab = aggbf + arow * 128 + lg * 8;
    #pragma unroll
    for (int kt = 0; kt < 4; ++kt)
      afrag[kt] = *(const bf16x8*)(ab + kt * 32);
  }
  __syncthreads();
  f32x4 acc[8];
  #pragma unroll
  for (int ct = 0; ct < 8; ++ct) {
    f32x4 a = {0.f, 0.f, 0.f, 0.f};
    const short* wb = &sW[(ct * 16 + lr) * 136 + lg * 8];
    #pragma unroll
    for (int kt = 0; kt < 4; ++kt) {
      bf16x8 bfr = *(const bf16x8*)(wb + kt * 32);
      a = __builtin_amdgcn_mfma_f32_16x16x32_bf16(afrag[kt], bfr, a, 0, 0, 0);
    }
    acc[ct] = a;
  }
  // epilogue: C/D layout col = lane&15 (+ct*16), row = lg*4 + reg
  int belr[4]; float dcv[4]; int rowv[4];
  #pragma unroll
  for (int r = 0; r < 4; ++r) {
    int gr = row0 + lg * 4 + r;
    rowv[r] = gr;
    int cl = min(gr, NSEQ - 1);
    belr[r] = bel[cl];
    dcv[r] = dinv_cnt[belr[r]];
  }
  #pragma unroll
  for (int ct = 0; ct < 8; ++ct) {
    int col = ct * 16 + lr;
    float bc = b_con[col], bi = b_inc[col];
    float s = 0.f, q = 0.f;
    #pragma unroll
    for (int r = 0; r < 4; ++r) {
      if (rowv[r] < NSEQ) {
        float o = acc[ct][r] + bc + fmaf(dcv[r], y_inc[belr[r] * D + col], bi);
        o = fmaxf(0.5f * o, 0.f);
        if (OUTBF) outB[rowv[r] * D + col] = (short)f2b(o);
        else       outF[rowv[r] * D + col] = o;
        s += o; q += o * o;
      }
    }
    s += __shfl_xor(s, 16); s += __shfl_xor(s, 32);
    q += __shfl_xor(q, 16); q += __shfl_xor(q, 32);
    if (lg == 0) {
      atomicAdd(&csum[col], s);
      atomicAdd(&csq[col], q);
    }
  }
  __syncthreads();
  if (t < D) {
    atomAddF(&stats[t], csum[t]);
    atomAddF(&stats[D + t], csq[t]);
  }
}

// ---------------- BN apply variants -------------------------------------------
__global__ __launch_bounds__(256) void k_bn_apply_bf(
    const uint32* __restrict__ pre,    // bf16 packed pre-BN
    const float* __restrict__ stats,
    const float* __restrict__ g, const float* __restrict__ beta,
    uint32* __restrict__ xb) {         // bf16 packed post-BN
  int i = blockIdx.x * 256 + threadIdx.x;   // 4-col group index
  if (i >= NSEQ * D / 4) return;
  int c = (i * 4) & (D - 1);
  uint2 u = ((const uint2*)pre)[i];
  float v0 = blo(u.x), v1 = bhi(u.x), v2 = blo(u.y), v3 = bhi(u.y);
  float4 s = *(const float4*)&stats[c];
  float4 q = *(const float4*)&stats[D + c];
  float4 gg = *(const float4*)&g[c];
  float4 bb = *(const float4*)&beta[c];
  const float invN = 1.f / (float)NSEQ;
  float m, var, a;
  m = s.x * invN; var = q.x * invN - m * m; a = rsqrtf(var + BN_EPS) * gg.x; v0 = (v0 - m) * a + bb.x;
  m = s.y * invN; var = q.y * invN - m * m; a = rsqrtf(var + BN_EPS) * gg.y; v1 = (v1 - m) * a + bb.y;
  m = s.z * invN; var = q.z * invN - m * m; a = rsqrtf(var + BN_EPS) * gg.z; v2 = (v2 - m) * a + bb.z;
  m = s.w * invN; var = q.w * invN - m * m; a = rsqrtf(var + BN_EPS) * gg.w; v3 = (v3 - m) * a + bb.w;
  uint32 o0 = (uint32)f2b(v0) | ((uint32)f2b(v1) << 16);
  uint32 o1 = (uint32)f2b(v2) | ((uint32)f2b(v3) << 16);
  ((uint2*)xb)[i] = make_uint2(o0, o1);
}

__global__ __launch_bounds__(256) void k_bn_apply(float* __restrict__ buf,
                                                  const float* __restrict__ stats,
                                                  const float* __restrict__ g,
                                                  const float* __restrict__ beta) {
  int i = blockIdx.x * 256 + threadIdx.x;
  if (i >= NSEQ * D / 4) return;
  int c = (i * 4) & (D - 1);
  float4 v = ((float4*)buf)[i];
  float4 s = *(const float4*)&stats[c];
  float4 q = *(const float4*)&stats[D + c];
  float4 gg = *(const float4*)&g[c];
  float4 bb = *(const float4*)&beta[c];
  const float invN = 1.f / (float)NSEQ;
  float m, var, a;
  m = s.x * invN; var = q.x * invN - m * m; a = rsqrtf(var + BN_EPS) * gg.x; v.x = (v.x - m) * a + bb.x;
  m = s.y * invN; var = q.y * invN - m * m; a = rsqrtf(var + BN_EPS) * gg.y; v.y = (v.y - m) * a + bb.y;
  m = s.z * invN; var = q.z * invN - m * m; a = rsqrtf(var + BN_EPS) * gg.z; v.z = (v.z - m) * a + bb.z;
  m = s.w * invN; var = q.w * invN - m * m; a = rsqrtf(var + BN_EPS) * gg.w; v.w = (v.w - m) * a + bb.w;
  ((float4*)buf)[i] = v;
}

// ---------------- launch ------------------------------------------------------
extern "C" void kernel_launch(void* const* d_in, const int* in_sizes, int n_in,
                              void* d_out, int out_size, void* d_ws, size_t ws_size,
                              hipStream_t stream) {
  const float* x_seq   = (const float*)d_in[0];
  const float* x_label = (const float*)d_in[1];
  const float* W1_bel  = (const float*)d_in[2];
  const float* b1_bel  = (const float*)d_in[3];
  const float* W1_inc  = (const float*)d_in[4];
  const float* b1_inc  = (const float*)d_in[5];
  const float* W1_con  = (const float*)d_in[6];
  const float* b1_con  = (const float*)d_in[7];
  const float* g1s     = (const float*)d_in[8];
  const float* beta1s  = (const float*)d_in[9];
  const float* g1l     = (const float*)d_in[10];
  const float* beta1l  = (const float*)d_in[11];
  const float* W2_bel  = (const float*)d_in[12];
  const float* b2_bel  = (const float*)d_in[13];
  const float* W2_inc  = (const float*)d_in[14];
  const float* b2_inc  = (const float*)d_in[15];
  const float* W2_con  = (const float*)d_in[16];
  const float* b2_con  = (const float*)d_in[17];
  const float* g2s     = (const float*)d_in[18];
  const float* beta2s  = (const float*)d_in[19];
  const float* g2l     = (const float*)d_in[20];
  const float* beta2l  = (const float*)d_in[21];
  const int* bel       = (const int*)d_in[22];
  const int* con_src   = (const int*)d_in[23];
  const int* con_dst   = (const int*)d_in[24];
  float* out = (float*)d_out;

  char* ws = (char*)d_ws;
  short*  aggbf    = (short*) (ws);                  // 25,600,000 B
  short*  h1pre    = (short*) (ws + 25600000);       // 25,600,000 B
  uint32* bpair    = (uint32*)(ws + 32000000);       //  8,028,160 B (dead after binB)
  int*    esrc     = (int*)   (ws + 51200000);       //  6,400,000 B
  // ---- zeroed region start (469,632 B) ----
  int*    deg_out    = (int*)  (ws + 57600000);
  int*    cnt_lab    = (int*)  (ws + 58000000);
  int*    bucket_cnt = (int*)  (ws + 58001024);
  float*  lab_agg1   = (float*)(ws + 58002048);
  float*  lab_agg2   = (float*)(ws + 58034816);
  float*  stats1     = (float*)(ws + 58067584);
  float*  stats2     = (float*)(ws + 58068608);
  // ---- zeroed region end ----
  float*  dinv_out = (float*)(ws + 58069632);
  float*  dinv_in  = (float*)(ws + 58469632);
  float*  dinv_cnt = (float*)(ws + 58869632);
  int*    bbase    = (int*)  (ws + 58869888);
  int*    off      = (int*)  (ws + 58870912);
  float*  y_inc1   = (float*)(ws + 59271040);
  float*  y_inc2   = (float*)(ws + 59303808);
  float*  h_l1     = (float*)(ws + 59336576);
  short*  wT1      = (short*)(ws + 59369344);        // 32,768 B
  short*  wT2      = (short*)(ws + 59402112);        // 32,768 B
  // end: 59,434,880 B

  uint32* xb = (uint32*)out;   // bf16 features in d_out[0..25.6MB)
  float* belp1 = (float*)ws;   // overwritten by con_agg afterwards
  float* belp2 = (float*)ws;

  hipMemsetAsync(ws + 57600000, 0, 469632, stream);

  // CSR build + degrees + casts
  k_label_hist<<<256, 256, 0, stream>>>(bel, cnt_lab);
  k_binA      <<<(ECON + EPB - 1) / EPB, 256, 0, stream>>>(con_src, con_dst,
                                                           deg_out, bucket_cnt, bpair);
  k_bscan     <<<1, 256, 0, stream>>>(bucket_cnt, bbase, cnt_lab, dinv_cnt);
  k_binB      <<<NB, 256, 0, stream>>>(bpair, bucket_cnt, bbase, deg_out,
                                       off, dinv_in, dinv_out, esrc);
  k_cast      <<<(NSEQ * D / 4 + 255) / 256, 256, 0, stream>>>(x_seq, xb);
  k_prep_w    <<<128, 256, 0, stream>>>(W1_con, W2_con, wT1, wT2);

  // ---- layer 1 ----
  k_label_agg <<<512, 256, 0, stream>>>(xb, bel, lab_agg1);
  k_mm        <<<32, 256, 0, stream>>>(x_label, nullptr, W1_inc, nullptr, y_inc1, 128, 0);
  k_mm        <<<32, 256, 0, stream>>>(lab_agg1, dinv_cnt, W1_bel, b1_bel, belp1, 128, 1);
  k_label_bn  <<<1, 256, 0, stream>>>(belp1, g1l, beta1l, h_l1, 128);
  k_con_agg_bf<<<NSEQ / 4, 256, 0, stream>>>(xb, esrc, off, dinv_out, dinv_in,
                                             (uint32*)aggbf);
  k_gemm_mfma<1><<<(NSEQ + 63) / 64, 256, 0, stream>>>(
                  aggbf, wT1, b1_con, y_inc1, b1_inc, dinv_cnt, bel,
                  nullptr, h1pre, stats1);
  k_bn_apply_bf<<<(NSEQ * D / 4 + 255) / 256, 256, 0, stream>>>(
                  (uint32*)h1pre, stats1, g1s, beta1s, xb);   // xb := h1 bf16

  // ---- layer 2 ----
  k_label_agg <<<512, 256, 0, stream>>>(xb, bel, lab_agg2);
  k_mm        <<<32, 256, 0, stream>>>(h_l1, nullptr, W2_inc, nullptr, y_inc2, 128, 0);
  k_mm        <<<16, 256, 0, stream>>>(lab_agg2, dinv_cnt, W2_bel, b2_bel, belp2, 64, 1);
  k_label_bn  <<<1, 256, 0, stream>>>(belp2, g2l, beta2l, out + (size_t)NSEQ * D, 64);
  k_con_agg_bf<<<NSEQ / 4, 256, 0, stream>>>(xb, esrc, off, dinv_out, dinv_in,
                                             (uint32*)aggbf);
  k_gemm_mfma<0><<<(NSEQ + 63) / 64, 256, 0, stream>>>(
                  aggbf, wT2, b2_con, y_inc2, b2_inc, dinv_cnt, bel,
                  out, nullptr, stats2);
  k_bn_apply  <<<(NSEQ * D / 4 + 255) / 256, 256, 0, stream>>>(out, stats2, g2s, beta2s);
}

// Round 7
// 552.441 us; speedup vs baseline: 2.0982x; 1.1117x over previous
//
#include <hip/hip_runtime.h>
#include <hip/hip_bf16.h>

#define NSEQ 100000
#define NLAB 64
#define ECON 1600000
#define D 128
#define BN_EPS 1e-5f

#define NB 196        // dst buckets
#define BW 512        // dst per bucket (NB*BW >= NSEQ)
#define BCAP 10240    // packed-record capacity per bucket
#define EPB 4096      // edges per block in k_binA
#define NPART 32      // rotating partial buffers for atomic flushes

typedef unsigned int uint32;
typedef __attribute__((ext_vector_type(8))) short bf16x8;
typedef __attribute__((ext_vector_type(4))) float f32x4;

// ---------------- helpers ----------------
__device__ __forceinline__ void atomAddF(float* p, float v) {
  unsafeAtomicAdd(p, v);  // native global_atomic_add_f32
}
__device__ __forceinline__ float blo(uint32 u) {
  union { uint32 u; float f; } c; c.u = u << 16; return c.f;
}
__device__ __forceinline__ float bhi(uint32 u) {
  union { uint32 u; float f; } c; c.u = u & 0xFFFF0000u; return c.f;
}
__device__ __forceinline__ unsigned short f2b(float f) {
  __hip_bfloat16 h = __float2bfloat16(f);   // RNE
  union { __hip_bfloat16 h; unsigned short s; } c; c.h = h; return c.s;
}

// ---------------- label histogram ----------------
__global__ __launch_bounds__(256) void k_label_hist(const int* __restrict__ lab, int* cnt) {
  __shared__ int h[NLAB];
  if (threadIdx.x < NLAB) h[threadIdx.x] = 0;
  __syncthreads();
  for (int i = blockIdx.x * 256 + threadIdx.x; i < NSEQ; i += gridDim.x * 256)
    atomicAdd(&h[lab[i]], 1);
  __syncthreads();
  if (threadIdx.x < NLAB) atomicAdd(&cnt[threadIdx.x], h[threadIdx.x]);
}

// ---------------- CSR build pass A: bucket edges by dst ----------------------
__global__ __launch_bounds__(256) void k_binA(const int* __restrict__ src,
                                              const int* __restrict__ dst,
                                              int* deg_out, int* bucket_cnt,
                                              uint32* __restrict__ bpair) {
  __shared__ int hist[NB];
  __shared__ int base[NB];
  int t = threadIdx.x;
  for (int i = t; i < NB; i += 256) hist[i] = 0;
  __syncthreads();
  int e0 = blockIdx.x * EPB;
  int e1 = min(e0 + EPB, ECON);
  for (int e = e0 + t; e < e1; e += 256) {
    int d = dst[e];
    atomicAdd(&hist[d >> 9], 1);
    atomicAdd(&deg_out[src[e]], 1);     // global, fire-and-forget
  }
  __syncthreads();
  for (int i = t; i < NB; i += 256) {
    int c = hist[i];
    base[i] = (c > 0) ? atomicAdd(&bucket_cnt[i], c) : 0;
    hist[i] = 0;                        // reuse as local cursor
  }
  __syncthreads();
  for (int e = e0 + t; e < e1; e += 256) {   // 2nd read: L2-hot
    int d = dst[e];
    int b = d >> 9;
    int p = base[b] + atomicAdd(&hist[b], 1);
    bpair[b * BCAP + p] = (uint32)src[e] | ((uint32)(d & (BW - 1)) << 17);
  }
}

// ---------------- bucket-count scan (+ dinv_cnt) ------------------------------
__global__ __launch_bounds__(256) void k_bscan(const int* __restrict__ bucket_cnt,
                                               int* __restrict__ bbase,
                                               const int* __restrict__ cnt_lab,
                                               float* __restrict__ dinv_cnt) {
  __shared__ int s[NB];
  int t = threadIdx.x;
  if (t < NB) s[t] = bucket_cnt[t];
  __syncthreads();
  if (t == 0) {
    int acc = 0;
    for (int i = 0; i < NB; ++i) { bbase[i] = acc; acc += s[i]; }
    bbase[NB] = acc;
  }
  if (t < NLAB) { int c = cnt_lab[t]; dinv_cnt[t] = c > 0 ? rsqrtf((float)c) : 0.f; }
}

// ---------------- CSR build pass B: per-bucket scatter + node data ------------
// NOTE: dinv_out ALIASES deg_out (read int, overwrite float per node) — no
// __restrict__ on those two params.
__global__ __launch_bounds__(256) void k_binB(const uint32* __restrict__ bpair,
                                              const int* __restrict__ bucket_cnt,
                                              const int* __restrict__ bbase,
                                              const int* deg_out,
                                              int* __restrict__ off,
                                              float* __restrict__ dinv_in,
                                              float* dinv_out,
                                              int* __restrict__ esrc) {
  __shared__ int deg[BW];
  __shared__ int loff[BW];
  __shared__ int cursor[BW];
  __shared__ int wsum[4];
  int b = blockIdx.x;
  int t = threadIdx.x;
  int cnt = bucket_cnt[b];
  int gbase = bbase[b];
  const uint32* bp = &bpair[(size_t)b * BCAP];
  deg[t] = 0; deg[t + 256] = 0;
  cursor[t] = 0; cursor[t + 256] = 0;
  __syncthreads();
  for (int i = t; i < cnt; i += 256)
    atomicAdd(&deg[bp[i] >> 17], 1);
  __syncthreads();
  int d0 = deg[2 * t], d1 = deg[2 * t + 1];
  int ps = d0 + d1;
  int lane = t & 63, w = t >> 6;
  int v = ps;
  #pragma unroll
  for (int o = 1; o < 64; o <<= 1) { int n = __shfl_up(v, o); if (lane >= o) v += n; }
  if (lane == 63) wsum[w] = v;
  __syncthreads();
  int wbase = 0;
  for (int i = 0; i < w; ++i) wbase += wsum[i];
  int excl = wbase + v - ps;
  loff[2 * t] = excl;
  loff[2 * t + 1] = excl + d0;
  __syncthreads();
  #pragma unroll
  for (int k = 0; k < 2; ++k) {
    int j = t + k * 256;
    int node = b * BW + j;
    if (node < NSEQ) {
      int dg = deg[j];
      off[node] = gbase + loff[j];
      dinv_in[node] = dg > 0 ? rsqrtf((float)dg) : 0.f;
      int dgo = deg_out[node];
      dinv_out[node] = dgo > 0 ? rsqrtf((float)dgo) : 0.f;   // alias overwrite, after read
    }
  }
  if (b == NB - 1 && t == 0) off[NSEQ] = ECON;
  for (int i = t; i < cnt; i += 256) {
    uint32 pk = bp[i];
    int dl = pk >> 17;
    int p = gbase + loff[dl] + atomicAdd(&cursor[dl], 1);
    esrc[p] = (int)(pk & 0x1FFFF);
  }
}

// ---------------- fused cast + label aggregation (layer 1) --------------------
// wave-per-row: lane cp handles cols 2cp, 2cp+1
__global__ __launch_bounds__(256) void k_cast_agg(
    const float* __restrict__ x, const int* __restrict__ lab,
    uint32* __restrict__ xb, float* __restrict__ labP) {
  __shared__ float acc[NLAB * D];
  int t = threadIdx.x;
  for (int i = t; i < NLAB * D; i += 256) acc[i] = 0.f;
  __syncthreads();
  int w = t >> 6, cp = t & 63;
  for (int r = blockIdx.x * 4 + w; r < NSEQ; r += gridDim.x * 4) {
    int l = lab[r];
    float2 v = ((const float2*)x)[r * 64 + cp];
    xb[r * 64 + cp] = (uint32)f2b(v.x) | ((uint32)f2b(v.y) << 16);
    atomicAdd(&acc[l * D + 2 * cp], v.x);
    atomicAdd(&acc[l * D + 2 * cp + 1], v.y);
  }
  __syncthreads();
  float* dst = labP + (blockIdx.x & (NPART - 1)) * (NLAB * D);
  for (int i = t; i < NLAB * D; i += 256) atomAddF(&dst[i], acc[i]);
}

// ---------------- label partial reduce (+ re-zero partials) -------------------
__global__ __launch_bounds__(256) void k_label_reduce(float* __restrict__ labP,
                                                      float* __restrict__ out) {
  int i = blockIdx.x * 256 + threadIdx.x;   // 8192 total
  float s = 0.f;
  #pragma unroll
  for (int k = 0; k < NPART; ++k) {
    s += labP[k * (NLAB * D) + i];
    labP[k * (NLAB * D) + i] = 0.f;         // ready for layer 2
  }
  out[i] = s;
}

// ---------------- weight prep: W (128x128 fp32, k-major) -> W^T bf16 ----------
__global__ __launch_bounds__(256) void k_prep_w(const float* __restrict__ W1,
                                                const float* __restrict__ W2,
                                                short* __restrict__ wT1,
                                                short* __restrict__ wT2) {
  int i = blockIdx.x * 256 + threadIdx.x;
  if (i < 16384) {
    int k = i >> 7, c = i & 127;
    wT1[c * 128 + k] = (short)f2b(W1[i]);
  } else if (i < 32768) {
    int j = i - 16384;
    int k = j >> 7, c = j & 127;
    wT2[c * 128 + k] = (short)f2b(W2[j]);
  }
}

// ---------------- small matmul: out[64][ncol] = op((A*rowscale) @ W + bias) ---
__global__ __launch_bounds__(256) void k_mm(
    const float* __restrict__ A, const float* __restrict__ rowscale,
    const float* __restrict__ W, const float* __restrict__ bias,
    float* __restrict__ out, int ncol, int relu) {
  __shared__ float sA[4 * D];
  int tid = threadIdx.x;
  int rows_pb = 256 / ncol;
  int row0 = blockIdx.x * rows_pb;
  int nload = rows_pb * D;
  for (int i = tid; i < nload; i += 256) {
    int r = row0 + (i >> 7);
    float s = rowscale ? rowscale[r] : 1.f;
    sA[i] = A[r * D + (i & 127)] * s;
  }
  __syncthreads();
  int j = tid & (ncol - 1);
  int r = tid / ncol;
  const float* a = &sA[r * D];
  const float* w = &W[j];
  float acc0 = 0.f, acc1 = 0.f, acc2 = 0.f, acc3 = 0.f;
  #pragma unroll 4
  for (int k = 0; k < D; k += 4) {
    acc0 = fmaf(a[k + 0], w[(k + 0) * ncol], acc0);
    acc1 = fmaf(a[k + 1], w[(k + 1) * ncol], acc1);
    acc2 = fmaf(a[k + 2], w[(k + 2) * ncol], acc2);
    acc3 = fmaf(a[k + 3], w[(k + 3) * ncol], acc3);
  }
  float s = (acc0 + acc1) + (acc2 + acc3);
  if (bias) s += bias[j];
  if (relu) s = fmaxf(s, 0.f);
  out[(row0 + r) * ncol + j] = s;
}

// ---------------- BN over 64 label rows ---------------------------------------
__global__ __launch_bounds__(256) void k_label_bn(
    const float* __restrict__ pre,
    const float* __restrict__ g, const float* __restrict__ beta,
    float* __restrict__ out, int ncol) {
  __shared__ float psum[256], psq[256];
  __shared__ float sa[128], sc[128];
  int tid = threadIdx.x;
  int ngrp = 256 / ncol;
  int grp = tid / ncol;
  int col = tid & (ncol - 1);
  float s = 0.f, q = 0.f;
  for (int r = grp; r < NLAB; r += ngrp) {
    float v = pre[r * ncol + col];
    s += v; q += v * v;
  }
  psum[tid] = s; psq[tid] = q;
  __syncthreads();
  if (tid < ncol) {
    float S = 0.f, Q = 0.f;
    for (int gi = 0; gi < ngrp; ++gi) { S += psum[gi * ncol + tid]; Q += psq[gi * ncol + tid]; }
    float m = S * (1.f / NLAB);
    float v = Q * (1.f / NLAB) - m * m;
    float a = rsqrtf(v + BN_EPS) * g[tid];
    sa[tid] = a; sc[tid] = beta[tid] - m * a;
  }
  __syncthreads();
  for (int i = tid; i < NLAB * ncol; i += 256) {
    int c = i & (ncol - 1);
    out[i] = pre[i] * sa[c] + sc[c];
  }
}

// ---------------- connected_to aggregation: bf16 in, bf16 out -----------------
__global__ __launch_bounds__(256) void k_con_agg_bf(
    const uint32* __restrict__ xb, const int* __restrict__ esrc,
    const int* __restrict__ off,
    const float* __restrict__ dinv_out, const float* __restrict__ dinv_in,
    uint32* __restrict__ outb) {
  int wid = (blockIdx.x * 256 + threadIdx.x) >> 6;   // dst node
  int lane = threadIdx.x & 63;
  if (wid >= NSEQ) return;
  int e0 = off[wid], e1 = off[wid + 1];
  float ax = 0.f, ay = 0.f;
  int e = e0;
  for (; e + 3 < e1; e += 4) {
    int s0 = esrc[e], s1 = esrc[e + 1], s2 = esrc[e + 2], s3 = esrc[e + 3];
    float w0 = dinv_out[s0], w1 = dinv_out[s1], w2 = dinv_out[s2], w3 = dinv_out[s3];
    uint32 u0 = xb[s0 * 64 + lane];
    uint32 u1 = xb[s1 * 64 + lane];
    uint32 u2 = xb[s2 * 64 + lane];
    uint32 u3 = xb[s3 * 64 + lane];
    ax += blo(u0) * w0 + blo(u1) * w1 + blo(u2) * w2 + blo(u3) * w3;
    ay += bhi(u0) * w0 + bhi(u1) * w1 + bhi(u2) * w2 + bhi(u3) * w3;
  }
  for (; e < e1; ++e) {
    int s0 = esrc[e];
    float w0 = dinv_out[s0];
    uint32 u0 = xb[s0 * 64 + lane];
    ax += blo(u0) * w0;
    ay += bhi(u0) * w0;
  }
  float di = dinv_in[wid];
  uint32 p = (uint32)f2b(ax * di) | ((uint32)f2b(ay * di) << 16);
  outb[wid * 64 + lane] = p;
}

// ---------------- MFMA GEMM + epilogue + BN partial stats ----------------------
template <int OUTBF>
__global__ __launch_bounds__(256) void k_gemm_mfma(
    const short* __restrict__ aggbf,    // NSEQ x 128 bf16
    const short* __restrict__ wT,       // 128(col) x 128(k) bf16
    const float* __restrict__ b_con,
    const float* __restrict__ y_inc,    // 64x128 fp32
    const float* __restrict__ b_inc,
    const float* __restrict__ dinv_cnt,
    const int* __restrict__ bel,
    float* __restrict__ outF,           // fp32 out (OUTBF=0)
    short* __restrict__ outB,           // bf16 out (OUTBF=1)
    float* __restrict__ statsP) {       // NPART x [sum 128][sumsq 128]
  __shared__ short sW[128 * 136];       // 272B row stride
  __shared__ float csum[D], csq[D];
  int t = threadIdx.x;
  {
    const uint4* src = (const uint4*)wT;   // 2048 uint4, 16 per row
    for (int i = t; i < 2048; i += 256) {
      int row = i >> 4, part = i & 15;
      *(uint4*)&sW[row * 136 + part * 8] = src[i];
    }
  }
  if (t < D) { csum[t] = 0.f; csq[t] = 0.f; }
  int w = t >> 6, l = t & 63;
  int lr = l & 15, lg = l >> 4;
  int row0 = blockIdx.x * 64 + w * 16;
  bf16x8 afrag[4];
  {
    int arow = min(row0 + lr, NSEQ - 1);
    const short* ab = aggbf + arow * 128 + lg * 8;
    #pragma unroll
    for (int kt = 0; kt < 4; ++kt)
      afrag[kt] = *(const bf16x8*)(ab + kt * 32);
  }
  __syncthreads();
  f32x4 acc[8];
  #pragma unroll
  for (int ct = 0; ct < 8; ++ct) {
    f32x4 a = {0.f, 0.f, 0.f, 0.f};
    const short* wb = &sW[(ct * 16 + lr) * 136 + lg * 8];
    #pragma unroll
    for (int kt = 0; kt < 4; ++kt) {
      bf16x8 bfr = *(const bf16x8*)(wb + kt * 32);
      a = __builtin_amdgcn_mfma_f32_16x16x32_bf16(afrag[kt], bfr, a, 0, 0, 0);
    }
    acc[ct] = a;
  }
  int belr[4]; float dcv[4]; int rowv[4];
  #pragma unroll
  for (int r = 0; r < 4; ++r) {
    int gr = row0 + lg * 4 + r;
    rowv[r] = gr;
    int cl = min(gr, NSEQ - 1);
    belr[r] = bel[cl];
    dcv[r] = dinv_cnt[belr[r]];
  }
  #pragma unroll
  for (int ct = 0; ct < 8; ++ct) {
    int col = ct * 16 + lr;
    float bc = b_con[col], bi = b_inc[col];
    float s = 0.f, q = 0.f;
    #pragma unroll
    for (int r = 0; r < 4; ++r) {
      if (rowv[r] < NSEQ) {
        float o = acc[ct][r] + bc + fmaf(dcv[r], y_inc[belr[r] * D + col], bi);
        o = fmaxf(0.5f * o, 0.f);
        if (OUTBF) outB[rowv[r] * D + col] = (short)f2b(o);
        else       outF[rowv[r] * D + col] = o;
        s += o; q += o * o;
      }
    }
    s += __shfl_xor(s, 16); s += __shfl_xor(s, 32);
    q += __shfl_xor(q, 16); q += __shfl_xor(q, 32);
    if (lg == 0) {
      atomicAdd(&csum[col], s);
      atomicAdd(&csq[col], q);
    }
  }
  __syncthreads();
  float* sp = statsP + (blockIdx.x & (NPART - 1)) * 256;
  if (t < D) {
    atomAddF(&sp[t], csum[t]);
    atomAddF(&sp[D + t], csq[t]);
  }
}

// ---------------- fused BN-apply + cast + label agg (layer 2 input) ------------
// reads bf16 pre-BN, reduces statsP per-lane, writes bf16 post-BN, accumulates
// label partials.
__global__ __launch_bounds__(256) void k_bnagg(
    const uint32* __restrict__ pre, const float* __restrict__ statsP,
    const float* __restrict__ g, const float* __restrict__ beta,
    const int* __restrict__ lab,
    uint32* __restrict__ xb, float* __restrict__ labP) {
  __shared__ float acc[NLAB * D];
  int t = threadIdx.x;
  for (int i = t; i < NLAB * D; i += 256) acc[i] = 0.f;
  int w = t >> 6, cp = t & 63;
  int c0 = 2 * cp, c1 = 2 * cp + 1;
  float s0 = 0.f, q0 = 0.f, s1 = 0.f, q1 = 0.f;
  #pragma unroll
  for (int k = 0; k < NPART; ++k) {
    const float* sp = statsP + k * 256;
    s0 += sp[c0]; q0 += sp[128 + c0];
    s1 += sp[c1]; q1 += sp[128 + c1];
  }
  const float invN = 1.f / (float)NSEQ;
  float m0 = s0 * invN, m1 = s1 * invN;
  float a0 = rsqrtf(q0 * invN - m0 * m0 + BN_EPS) * g[c0];
  float a1 = rsqrtf(q1 * invN - m1 * m1 + BN_EPS) * g[c1];
  float cc0 = beta[c0] - m0 * a0;
  float cc1 = beta[c1] - m1 * a1;
  __syncthreads();
  for (int r = blockIdx.x * 4 + w; r < NSEQ; r += gridDim.x * 4) {
    int l = lab[r];
    uint32 u = pre[r * 64 + cp];
    float v0 = blo(u) * a0 + cc0;
    float v1 = bhi(u) * a1 + cc1;
    xb[r * 64 + cp] = (uint32)f2b(v0) | ((uint32)f2b(v1) << 16);
    atomicAdd(&acc[l * D + c0], v0);
    atomicAdd(&acc[l * D + c1], v1);
  }
  __syncthreads();
  float* dst = labP + (blockIdx.x & (NPART - 1)) * (NLAB * D);
  for (int i = t; i < NLAB * D; i += 256) atomAddF(&dst[i], acc[i]);
}

// ---------------- final BN apply (fp32 in place, per-lane stats reduce) --------
__global__ __launch_bounds__(256) void k_bn_apply2(
    float* __restrict__ buf, const float* __restrict__ statsP,
    const float* __restrict__ g, const float* __restrict__ beta) {
  int t = threadIdx.x;
  int w = t >> 6, cp = t & 63;
  int c0 = 2 * cp, c1 = 2 * cp + 1;
  float s0 = 0.f, q0 = 0.f, s1 = 0.f, q1 = 0.f;
  #pragma unroll
  for (int k = 0; k < NPART; ++k) {
    const float* sp = statsP + k * 256;
    s0 += sp[c0]; q0 += sp[128 + c0];
    s1 += sp[c1]; q1 += sp[128 + c1];
  }
  const float invN = 1.f / (float)NSEQ;
  float m0 = s0 * invN, m1 = s1 * invN;
  float a0 = rsqrtf(q0 * invN - m0 * m0 + BN_EPS) * g[c0];
  float a1 = rsqrtf(q1 * invN - m1 * m1 + BN_EPS) * g[c1];
  float cc0 = beta[c0] - m0 * a0;
  float cc1 = beta[c1] - m1 * a1;
  for (int r = blockIdx.x * 4 + w; r < NSEQ; r += gridDim.x * 4) {
    float2 v = ((float2*)buf)[r * 64 + cp];
    v.x = v.x * a0 + cc0;
    v.y = v.y * a1 + cc1;
    ((float2*)buf)[r * 64 + cp] = v;
  }
}

// ---------------- launch ------------------------------------------------------
extern "C" void kernel_launch(void* const* d_in, const int* in_sizes, int n_in,
                              void* d_out, int out_size, void* d_ws, size_t ws_size,
                              hipStream_t stream) {
  const float* x_seq   = (const float*)d_in[0];
  const float* x_label = (const float*)d_in[1];
  const float* W1_bel  = (const float*)d_in[2];
  const float* b1_bel  = (const float*)d_in[3];
  const float* W1_inc  = (const float*)d_in[4];
  const float* b1_inc  = (const float*)d_in[5];
  const float* W1_con  = (const float*)d_in[6];
  const float* b1_con  = (const float*)d_in[7];
  const float* g1s     = (const float*)d_in[8];
  const float* beta1s  = (const float*)d_in[9];
  const float* g1l     = (const float*)d_in[10];
  const float* beta1l  = (const float*)d_in[11];
  const float* W2_bel  = (const float*)d_in[12];
  const float* b2_bel  = (const float*)d_in[13];
  const float* W2_inc  = (const float*)d_in[14];
  const float* b2_inc  = (const float*)d_in[15];
  const float* W2_con  = (const float*)d_in[16];
  const float* b2_con  = (const float*)d_in[17];
  const float* g2s     = (const float*)d_in[18];
  const float* beta2s  = (const float*)d_in[19];
  const float* g2l     = (const float*)d_in[20];
  const float* beta2l  = (const float*)d_in[21];
  const int* bel       = (const int*)d_in[22];
  const int* con_src   = (const int*)d_in[23];
  const int* con_dst   = (const int*)d_in[24];
  float* out = (float*)d_out;

  char* ws = (char*)d_ws;
  short*  aggbf    = (short*) (ws);                  // 25,600,000 B
  short*  h1pre    = (short*) (ws + 25600000);       // 25,600,000 B
  uint32* bpair    = (uint32*)(ws + 32000000);       //  8,028,160 B (dead after binB)
  int*    esrc     = (int*)   (ws + 51200000);       //  6,400,000 B
  // ---- zeroed region start (1,516,160 B) ----
  int*    deg_out    = (int*)  (ws + 57600000);      // 400,000 (aliased by dinv_out)
  int*    cnt_lab    = (int*)  (ws + 58000000);      //   1,024
  int*    bucket_cnt = (int*)  (ws + 58001024);      //   1,024
  float*  labP       = (float*)(ws + 58002048);      // 1,048,576 (32 x 8192 f32)
  float*  statsP1    = (float*)(ws + 59050624);      //  32,768 (32 x 256 f32)
  float*  statsP2    = (float*)(ws + 59083392);      //  32,768
  // ---- zeroed region end (59,116,160) ----
  float*  lab_agg1 = (float*)(ws + 59116160);        //  32,768
  float*  lab_agg2 = (float*)(ws + 59148928);        //  32,768
  float*  dinv_in  = (float*)(ws + 59181696);        // 400,000
  float*  dinv_cnt = (float*)(ws + 59581696);        //     256
  int*    bbase    = (int*)  (ws + 59581952);        //   1,024
  int*    off      = (int*)  (ws + 59582976);        // 400,128
  float*  y_inc1   = (float*)(ws + 59983104);        //  32,768
  float*  y_inc2   = (float*)(ws + 60015872);        //  32,768
  float*  h_l1     = (float*)(ws + 60048640);        //  32,768
  short*  wT1      = (short*)(ws + 60081408);        //  32,768
  short*  wT2      = (short*)(ws + 60114176);        //  32,768
  // end: 60,146,944 B

  float* dinv_out = (float*)deg_out;   // alias: deg_out dead after k_binB reads it
  uint32* xb = (uint32*)out;           // bf16 features in d_out[0..25.6MB)
  float* belp1 = (float*)ws;           // transient, overwritten by con_agg
  float* belp2 = (float*)ws;

  hipMemsetAsync(ws + 57600000, 0, 1516160, stream);

  // CSR build + degrees + prep
  k_label_hist<<<256, 256, 0, stream>>>(bel, cnt_lab);
  k_binA      <<<(ECON + EPB - 1) / EPB, 256, 0, stream>>>(con_src, con_dst,
                                                           deg_out, bucket_cnt, bpair);
  k_bscan     <<<1, 256, 0, stream>>>(bucket_cnt, bbase, cnt_lab, dinv_cnt);
  k_binB      <<<NB, 256, 0, stream>>>(bpair, bucket_cnt, bbase, deg_out,
                                       off, dinv_in, dinv_out, esrc);
  k_cast_agg  <<<1024, 256, 0, stream>>>(x_seq, bel, xb, labP);
  k_prep_w    <<<128, 256, 0, stream>>>(W1_con, W2_con, wT1, wT2);

  // ---- layer 1 ----
  k_label_reduce<<<32, 256, 0, stream>>>(labP, lab_agg1);
  k_mm        <<<32, 256, 0, stream>>>(x_label, nullptr, W1_inc, nullptr, y_inc1, 128, 0);
  k_mm        <<<32, 256, 0, stream>>>(lab_agg1, dinv_cnt, W1_bel, b1_bel, belp1, 128, 1);
  k_label_bn  <<<1, 256, 0, stream>>>(belp1, g1l, beta1l, h_l1, 128);
  k_con_agg_bf<<<NSEQ / 4, 256, 0, stream>>>(xb, esrc, off, dinv_out, dinv_in,
                                             (uint32*)aggbf);
  k_gemm_mfma<1><<<(NSEQ + 63) / 64, 256, 0, stream>>>(
                  aggbf, wT1, b1_con, y_inc1, b1_inc, dinv_cnt, bel,
                  nullptr, h1pre, statsP1);
  k_bnagg     <<<1024, 256, 0, stream>>>((uint32*)h1pre, statsP1, g1s, beta1s,
                                         bel, xb, labP);   // xb := h1 bf16

  // ---- layer 2 ----
  k_label_reduce<<<32, 256, 0, stream>>>(labP, lab_agg2);
  k_mm        <<<32, 256, 0, stream>>>(h_l1, nullptr, W2_inc, nullptr, y_inc2, 128, 0);
  k_mm        <<<16, 256, 0, stream>>>(lab_agg2, dinv_cnt, W2_bel, b2_bel, belp2, 64, 1);
  k_label_bn  <<<1, 256, 0, stream>>>(belp2, g2l, beta2l, out + (size_t)NSEQ * D, 64);
  k_con_agg_bf<<<NSEQ / 4, 256, 0, stream>>>(xb, esrc, off, dinv_out, dinv_in,
                                             (uint32*)aggbf);
  k_gemm_mfma<0><<<(NSEQ + 63) / 64, 256, 0, stream>>>(
                  aggbf, wT2, b2_con, y_inc2, b2_inc, dinv_cnt, bel,
                  out, nullptr, statsP2);
  k_bn_apply2 <<<1024, 256, 0, stream>>>(out, statsP2, g2s, beta2s);
}

// Round 8
// 489.701 us; speedup vs baseline: 2.3670x; 1.1281x over previous
//
#include <hip/hip_runtime.h>
#include <hip/hip_bf16.h>

#define NSEQ 100000
#define NLAB 64
#define ECON 1600000
#define D 128
#define BN_EPS 1e-5f

#define NB 196        // dst buckets
#define BW 512        // dst per bucket (NB*BW >= NSEQ)
#define BCAP 10240    // packed-record capacity per bucket
#define EPB 4096      // edges per block in k_binA
#define NPART 32      // rotating partial buffers for stats flushes
#define RPB 4096      // rows per block in k_lab_scatter

typedef unsigned int uint32;
typedef __attribute__((ext_vector_type(8))) short bf16x8;
typedef __attribute__((ext_vector_type(4))) float f32x4;

// ---------------- helpers ----------------
__device__ __forceinline__ void atomAddF(float* p, float v) {
  unsafeAtomicAdd(p, v);  // native global_atomic_add_f32
}
__device__ __forceinline__ float blo(uint32 u) {
  union { uint32 u; float f; } c; c.u = u << 16; return c.f;
}
__device__ __forceinline__ float bhi(uint32 u) {
  union { uint32 u; float f; } c; c.u = u & 0xFFFF0000u; return c.f;
}
__device__ __forceinline__ unsigned short f2b(float f) {
  __hip_bfloat16 h = __float2bfloat16(f);   // RNE
  union { __hip_bfloat16 h; unsigned short s; } c; c.h = h; return c.s;
}

// ---------------- label histogram ----------------
__global__ __launch_bounds__(256) void k_label_hist(const int* __restrict__ lab, int* cnt) {
  __shared__ int h[NLAB];
  if (threadIdx.x < NLAB) h[threadIdx.x] = 0;
  __syncthreads();
  for (int i = blockIdx.x * 256 + threadIdx.x; i < NSEQ; i += gridDim.x * 256)
    atomicAdd(&h[lab[i]], 1);
  __syncthreads();
  if (threadIdx.x < NLAB) atomicAdd(&cnt[threadIdx.x], h[threadIdx.x]);
}

// ---------------- CSR build pass A: bucket edges by dst ----------------------
__global__ __launch_bounds__(256) void k_binA(const int* __restrict__ src,
                                              const int* __restrict__ dst,
                                              int* deg_out, int* bucket_cnt,
                                              uint32* __restrict__ bpair) {
  __shared__ int hist[NB];
  __shared__ int base[NB];
  int t = threadIdx.x;
  for (int i = t; i < NB; i += 256) hist[i] = 0;
  __syncthreads();
  int e0 = blockIdx.x * EPB;
  int e1 = min(e0 + EPB, ECON);
  for (int e = e0 + t; e < e1; e += 256) {
    int d = dst[e];
    atomicAdd(&hist[d >> 9], 1);
    atomicAdd(&deg_out[src[e]], 1);     // global, fire-and-forget
  }
  __syncthreads();
  for (int i = t; i < NB; i += 256) {
    int c = hist[i];
    base[i] = (c > 0) ? atomicAdd(&bucket_cnt[i], c) : 0;
    hist[i] = 0;                        // reuse as local cursor
  }
  __syncthreads();
  for (int e = e0 + t; e < e1; e += 256) {   // 2nd read: L2-hot
    int d = dst[e];
    int b = d >> 9;
    int p = base[b] + atomicAdd(&hist[b], 1);
    bpair[b * BCAP + p] = (uint32)src[e] | ((uint32)(d & (BW - 1)) << 17);
  }
}

// ---------------- scans: buckets, labels (+ dinv_cnt) -------------------------
__global__ __launch_bounds__(256) void k_bscan(const int* __restrict__ bucket_cnt,
                                               int* __restrict__ bbase,
                                               const int* __restrict__ cnt_lab,
                                               float* __restrict__ dinv_cnt,
                                               int* __restrict__ lab_base,
                                               int* __restrict__ lab_cursor) {
  int t = threadIdx.x;
  if (t == 0) {
    int acc = 0;
    for (int i = 0; i < NB; ++i) { bbase[i] = acc; acc += bucket_cnt[i]; }
    bbase[NB] = acc;
  }
  if (t == 1) {
    int acc = 0;
    for (int i = 0; i < NLAB; ++i) {
      lab_base[i] = acc; lab_cursor[i] = acc; acc += cnt_lab[i];
    }
    lab_base[NLAB] = acc;
  }
  if (t < NLAB) { int c = cnt_lab[t]; dinv_cnt[t] = c > 0 ? rsqrtf((float)c) : 0.f; }
}

// ---------------- CSR build pass B: per-bucket scatter + node data ------------
// NOTE: dinv_out ALIASES deg_out — no __restrict__ on those two params.
__global__ __launch_bounds__(256) void k_binB(const uint32* __restrict__ bpair,
                                              const int* __restrict__ bucket_cnt,
                                              const int* __restrict__ bbase,
                                              const int* deg_out,
                                              int* __restrict__ off,
                                              float* __restrict__ dinv_in,
                                              float* dinv_out,
                                              int* __restrict__ esrc) {
  __shared__ int deg[BW];
  __shared__ int loff[BW];
  __shared__ int cursor[BW];
  __shared__ int wsum[4];
  int b = blockIdx.x;
  int t = threadIdx.x;
  int cnt = bucket_cnt[b];
  int gbase = bbase[b];
  const uint32* bp = &bpair[(size_t)b * BCAP];
  deg[t] = 0; deg[t + 256] = 0;
  cursor[t] = 0; cursor[t + 256] = 0;
  __syncthreads();
  for (int i = t; i < cnt; i += 256)
    atomicAdd(&deg[bp[i] >> 17], 1);
  __syncthreads();
  int d0 = deg[2 * t], d1 = deg[2 * t + 1];
  int ps = d0 + d1;
  int lane = t & 63, w = t >> 6;
  int v = ps;
  #pragma unroll
  for (int o = 1; o < 64; o <<= 1) { int n = __shfl_up(v, o); if (lane >= o) v += n; }
  if (lane == 63) wsum[w] = v;
  __syncthreads();
  int wbase = 0;
  for (int i = 0; i < w; ++i) wbase += wsum[i];
  int excl = wbase + v - ps;
  loff[2 * t] = excl;
  loff[2 * t + 1] = excl + d0;
  __syncthreads();
  #pragma unroll
  for (int k = 0; k < 2; ++k) {
    int j = t + k * 256;
    int node = b * BW + j;
    if (node < NSEQ) {
      int dg = deg[j];
      off[node] = gbase + loff[j];
      dinv_in[node] = dg > 0 ? rsqrtf((float)dg) : 0.f;
      int dgo = deg_out[node];
      dinv_out[node] = dgo > 0 ? rsqrtf((float)dgo) : 0.f;   // alias overwrite, after read
    }
  }
  if (b == NB - 1 && t == 0) off[NSEQ] = ECON;
  for (int i = t; i < cnt; i += 256) {
    uint32 pk = bp[i];
    int dl = pk >> 17;
    int p = gbase + loff[dl] + atomicAdd(&cursor[dl], 1);
    esrc[p] = (int)(pk & 0x1FFFF);
  }
}

// ---------------- label counting sort: row indices grouped by label -----------
__global__ __launch_bounds__(256) void k_lab_scatter(const int* __restrict__ lab,
                                                     int* lab_cursor,
                                                     int* __restrict__ lab_sorted) {
  __shared__ int hist[NLAB], base[NLAB];
  int t = threadIdx.x;
  if (t < NLAB) hist[t] = 0;
  __syncthreads();
  int r0 = blockIdx.x * RPB, r1 = min(r0 + RPB, NSEQ);
  for (int r = r0 + t; r < r1; r += 256) atomicAdd(&hist[lab[r]], 1);
  __syncthreads();
  if (t < NLAB) {
    int c = hist[t];
    base[t] = (c > 0) ? atomicAdd(&lab_cursor[t], c) : 0;
    hist[t] = 0;
  }
  __syncthreads();
  for (int r = r0 + t; r < r1; r += 256) {
    int l = lab[r];
    int p = base[l] + atomicAdd(&hist[l], 1);
    lab_sorted[p] = r;
  }
}

// ---------------- label aggregation via sorted gather (no dense flush) --------
// grid = NLAB*8; block = 4 waves; 32 partitions per label, stride-32 row walk.
__global__ __launch_bounds__(256) void k_lab_agg(const uint32* __restrict__ xb,
                                                 const int* __restrict__ lab_sorted,
                                                 const int* __restrict__ lab_base,
                                                 float* __restrict__ lab_agg) {
  __shared__ float accs[4][D];
  int t = threadIdx.x;
  int l = blockIdx.x >> 3, p = blockIdx.x & 7;
  int w = t >> 6, cp = t & 63;
  int i0 = lab_base[l], i1 = lab_base[l + 1];
  float ax = 0.f, ay = 0.f;
  for (int i = i0 + p * 4 + w; i < i1; i += 32) {
    int r = lab_sorted[i];
    uint32 u = xb[r * 64 + cp];
    ax += blo(u); ay += bhi(u);
  }
  accs[w][2 * cp] = ax;
  accs[w][2 * cp + 1] = ay;
  __syncthreads();
  if (w == 0) {
    float s0 = accs[0][2 * cp] + accs[1][2 * cp] + accs[2][2 * cp] + accs[3][2 * cp];
    float s1 = accs[0][2 * cp + 1] + accs[1][2 * cp + 1] + accs[2][2 * cp + 1] + accs[3][2 * cp + 1];
    atomAddF(&lab_agg[l * D + 2 * cp], s0);
    atomAddF(&lab_agg[l * D + 2 * cp + 1], s1);
  }
}

// ---------------- fp32 -> bf16 cast (pure stream) ------------------------------
__global__ __launch_bounds__(256) void k_cast(const float* __restrict__ x,
                                              uint32* __restrict__ xb) {
  int i = blockIdx.x * 256 + threadIdx.x;     // float4 index
  if (i >= NSEQ * D / 4) return;
  float4 v = ((const float4*)x)[i];
  uint32 u0 = (uint32)f2b(v.x) | ((uint32)f2b(v.y) << 16);
  uint32 u1 = (uint32)f2b(v.z) | ((uint32)f2b(v.w) << 16);
  ((uint2*)xb)[i] = make_uint2(u0, u1);
}

// ---------------- weight prep: W (128x128 fp32, k-major) -> W^T bf16 ----------
__global__ __launch_bounds__(256) void k_prep_w(const float* __restrict__ W1,
                                                const float* __restrict__ W2,
                                                short* __restrict__ wT1,
                                                short* __restrict__ wT2) {
  int i = blockIdx.x * 256 + threadIdx.x;
  if (i < 16384) {
    int k = i >> 7, c = i & 127;
    wT1[c * 128 + k] = (short)f2b(W1[i]);
  } else if (i < 32768) {
    int j = i - 16384;
    int k = j >> 7, c = j & 127;
    wT2[c * 128 + k] = (short)f2b(W2[j]);
  }
}

// ---------------- small matmul: out[64][ncol] = op((A*rowscale) @ W + bias) ---
__global__ __launch_bounds__(256) void k_mm(
    const float* __restrict__ A, const float* __restrict__ rowscale,
    const float* __restrict__ W, const float* __restrict__ bias,
    float* __restrict__ out, int ncol, int relu) {
  __shared__ float sA[4 * D];
  int tid = threadIdx.x;
  int rows_pb = 256 / ncol;
  int row0 = blockIdx.x * rows_pb;
  int nload = rows_pb * D;
  for (int i = tid; i < nload; i += 256) {
    int r = row0 + (i >> 7);
    float s = rowscale ? rowscale[r] : 1.f;
    sA[i] = A[r * D + (i & 127)] * s;
  }
  __syncthreads();
  int j = tid & (ncol - 1);
  int r = tid / ncol;
  const float* a = &sA[r * D];
  const float* w = &W[j];
  float acc0 = 0.f, acc1 = 0.f, acc2 = 0.f, acc3 = 0.f;
  #pragma unroll 4
  for (int k = 0; k < D; k += 4) {
    acc0 = fmaf(a[k + 0], w[(k + 0) * ncol], acc0);
    acc1 = fmaf(a[k + 1], w[(k + 1) * ncol], acc1);
    acc2 = fmaf(a[k + 2], w[(k + 2) * ncol], acc2);
    acc3 = fmaf(a[k + 3], w[(k + 3) * ncol], acc3);
  }
  float s = (acc0 + acc1) + (acc2 + acc3);
  if (bias) s += bias[j];
  if (relu) s = fmaxf(s, 0.f);
  out[(row0 + r) * ncol + j] = s;
}

// ---------------- BN over 64 label rows ---------------------------------------
__global__ __launch_bounds__(256) void k_label_bn(
    const float* __restrict__ pre,
    const float* __restrict__ g, const float* __restrict__ beta,
    float* __restrict__ out, int ncol) {
  __shared__ float psum[256], psq[256];
  __shared__ float sa[128], sc[128];
  int tid = threadIdx.x;
  int ngrp = 256 / ncol;
  int grp = tid / ncol;
  int col = tid & (ncol - 1);
  float s = 0.f, q = 0.f;
  for (int r = grp; r < NLAB; r += ngrp) {
    float v = pre[r * ncol + col];
    s += v; q += v * v;
  }
  psum[tid] = s; psq[tid] = q;
  __syncthreads();
  if (tid < ncol) {
    float S = 0.f, Q = 0.f;
    for (int gi = 0; gi < ngrp; ++gi) { S += psum[gi * ncol + tid]; Q += psq[gi * ncol + tid]; }
    float m = S * (1.f / NLAB);
    float v = Q * (1.f / NLAB) - m * m;
    float a = rsqrtf(v + BN_EPS) * g[tid];
    sa[tid] = a; sc[tid] = beta[tid] - m * a;
  }
  __syncthreads();
  for (int i = tid; i < NLAB * ncol; i += 256) {
    int c = i & (ncol - 1);
    out[i] = pre[i] * sa[c] + sc[c];
  }
}

// ---------------- connected_to aggregation: bf16 in, bf16 out -----------------
__global__ __launch_bounds__(256) void k_con_agg_bf(
    const uint32* __restrict__ xb, const int* __restrict__ esrc,
    const int* __restrict__ off,
    const float* __restrict__ dinv_out, const float* __restrict__ dinv_in,
    uint32* __restrict__ outb) {
  int wid = (blockIdx.x * 256 + threadIdx.x) >> 6;   // dst node
  int lane = threadIdx.x & 63;
  if (wid >= NSEQ) return;
  int e0 = off[wid], e1 = off[wid + 1];
  float ax = 0.f, ay = 0.f;
  int e = e0;
  for (; e + 3 < e1; e += 4) {
    int s0 = esrc[e], s1 = esrc[e + 1], s2 = esrc[e + 2], s3 = esrc[e + 3];
    float w0 = dinv_out[s0], w1 = dinv_out[s1], w2 = dinv_out[s2], w3 = dinv_out[s3];
    uint32 u0 = xb[s0 * 64 + lane];
    uint32 u1 = xb[s1 * 64 + lane];
    uint32 u2 = xb[s2 * 64 + lane];
    uint32 u3 = xb[s3 * 64 + lane];
    ax += blo(u0) * w0 + blo(u1) * w1 + blo(u2) * w2 + blo(u3) * w3;
    ay += bhi(u0) * w0 + bhi(u1) * w1 + bhi(u2) * w2 + bhi(u3) * w3;
  }
  for (; e < e1; ++e) {
    int s0 = esrc[e];
    float w0 = dinv_out[s0];
    uint32 u0 = xb[s0 * 64 + lane];
    ax += blo(u0) * w0;
    ay += bhi(u0) * w0;
  }
  float di = dinv_in[wid];
  uint32 p = (uint32)f2b(ax * di) | ((uint32)f2b(ay * di) << 16);
  outb[wid * 64 + lane] = p;
}

// ---------------- MFMA GEMM + epilogue + BN partial stats ----------------------
template <int OUTBF>
__global__ __launch_bounds__(256) void k_gemm_mfma(
    const short* __restrict__ aggbf,    // NSEQ x 128 bf16
    const short* __restrict__ wT,       // 128(col) x 128(k) bf16
    const float* __restrict__ b_con,
    const float* __restrict__ y_inc,    // 64x128 fp32
    const float* __restrict__ b_inc,
    const float* __restrict__ dinv_cnt,
    const int* __restrict__ bel,
    float* __restrict__ outF,           // fp32 out (OUTBF=0)
    short* __restrict__ outB,           // bf16 out (OUTBF=1)
    float* __restrict__ statsP) {       // NPART x [sum 128][sumsq 128]
  __shared__ short sW[128 * 136];       // 272B row stride
  __shared__ float csum[D], csq[D];
  int t = threadIdx.x;
  {
    const uint4* src = (const uint4*)wT;   // 2048 uint4, 16 per row
    for (int i = t; i < 2048; i += 256) {
      int row = i >> 4, part = i & 15;
      *(uint4*)&sW[row * 136 + part * 8] = src[i];
    }
  }
  if (t < D) { csum[t] = 0.f; csq[t] = 0.f; }
  int w = t >> 6, l = t & 63;
  int lr = l & 15, lg = l >> 4;
  int row0 = blockIdx.x * 64 + w * 16;
  bf16x8 afrag[4];
  {
    int arow = min(row0 + lr, NSEQ - 1);
    const short* ab = aggbf + arow * 128 + lg * 8;
    #pragma unroll
    for (int kt = 0; kt < 4; ++kt)
      afrag[kt] = *(const bf16x8*)(ab + kt * 32);
  }
  __syncthreads();
  f32x4 acc[8];
  #pragma unroll
  for (int ct = 0; ct < 8; ++ct) {
    f32x4 a = {0.f, 0.f, 0.f, 0.f};
    const short* wb = &sW[(ct * 16 + lr) * 136 + lg * 8];
    #pragma unroll
    for (int kt = 0; kt < 4; ++kt) {
      bf16x8 bfr = *(const bf16x8*)(wb + kt * 32);
      a = __builtin_amdgcn_mfma_f32_16x16x32_bf16(afrag[kt], bfr, a, 0, 0, 0);
    }
    acc[ct] = a;
  }
  int belr[4]; float dcv[4]; int rowv[4];
  #pragma unroll
  for (int r = 0; r < 4; ++r) {
    int gr = row0 + lg * 4 + r;
    rowv[r] = gr;
    int cl = min(gr, NSEQ - 1);
    belr[r] = bel[cl];
    dcv[r] = dinv_cnt[belr[r]];
  }
  #pragma unroll
  for (int ct = 0; ct < 8; ++ct) {
    int col = ct * 16 + lr;
    float bc = b_con[col], bi = b_inc[col];
    float s = 0.f, q = 0.f;
    #pragma unroll
    for (int r = 0; r < 4; ++r) {
      if (rowv[r] < NSEQ) {
        float o = acc[ct][r] + bc + fmaf(dcv[r], y_inc[belr[r] * D + col], bi);
        o = fmaxf(0.5f * o, 0.f);
        if (OUTBF) outB[rowv[r] * D + col] = (short)f2b(o);
        else       outF[rowv[r] * D + col] = o;
        s += o; q += o * o;
      }
    }
    s += __shfl_xor(s, 16); s += __shfl_xor(s, 32);
    q += __shfl_xor(q, 16); q += __shfl_xor(q, 32);
    if (lg == 0) {
      atomicAdd(&csum[col], s);
      atomicAdd(&csq[col], q);
    }
  }
  __syncthreads();
  float* sp = statsP + (blockIdx.x & (NPART - 1)) * 256;
  if (t < D) {
    atomAddF(&sp[t], csum[t]);
    atomAddF(&sp[D + t], csq[t]);
  }
}

// ---------------- BN apply, bf16 in -> bf16 out (pure stream) ------------------
__global__ __launch_bounds__(256) void k_bn_apply_bf(
    const uint32* __restrict__ pre, const float* __restrict__ statsP,
    const float* __restrict__ g, const float* __restrict__ beta,
    uint32* __restrict__ xb) {
  int t = threadIdx.x;
  int w = t >> 6, cp = t & 63;
  int c0 = 2 * cp, c1 = 2 * cp + 1;
  float s0 = 0.f, q0 = 0.f, s1 = 0.f, q1 = 0.f;
  #pragma unroll
  for (int k = 0; k < NPART; ++k) {
    const float* sp = statsP + k * 256;
    s0 += sp[c0]; q0 += sp[128 + c0];
    s1 += sp[c1]; q1 += sp[128 + c1];
  }
  const float invN = 1.f / (float)NSEQ;
  float m0 = s0 * invN, m1 = s1 * invN;
  float a0 = rsqrtf(q0 * invN - m0 * m0 + BN_EPS) * g[c0];
  float a1 = rsqrtf(q1 * invN - m1 * m1 + BN_EPS) * g[c1];
  float cc0 = beta[c0] - m0 * a0;
  float cc1 = beta[c1] - m1 * a1;
  for (int r = blockIdx.x * 4 + w; r < NSEQ; r += gridDim.x * 4) {
    uint32 u = pre[r * 64 + cp];
    float v0 = blo(u) * a0 + cc0;
    float v1 = bhi(u) * a1 + cc1;
    xb[r * 64 + cp] = (uint32)f2b(v0) | ((uint32)f2b(v1) << 16);
  }
}

// ---------------- final BN apply (fp32 in place, per-lane stats reduce) --------
__global__ __launch_bounds__(256) void k_bn_apply2(
    float* __restrict__ buf, const float* __restrict__ statsP,
    const float* __restrict__ g, const float* __restrict__ beta) {
  int t = threadIdx.x;
  int w = t >> 6, cp = t & 63;
  int c0 = 2 * cp, c1 = 2 * cp + 1;
  float s0 = 0.f, q0 = 0.f, s1 = 0.f, q1 = 0.f;
  #pragma unroll
  for (int k = 0; k < NPART; ++k) {
    const float* sp = statsP + k * 256;
    s0 += sp[c0]; q0 += sp[128 + c0];
    s1 += sp[c1]; q1 += sp[128 + c1];
  }
  const float invN = 1.f / (float)NSEQ;
  float m0 = s0 * invN, m1 = s1 * invN;
  float a0 = rsqrtf(q0 * invN - m0 * m0 + BN_EPS) * g[c0];
  float a1 = rsqrtf(q1 * invN - m1 * m1 + BN_EPS) * g[c1];
  float cc0 = beta[c0] - m0 * a0;
  float cc1 = beta[c1] - m1 * a1;
  for (int r = blockIdx.x * 4 + w; r < NSEQ; r += gridDim.x * 4) {
    float2 v = ((float2*)buf)[r * 64 + cp];
    v.x = v.x * a0 + cc0;
    v.y = v.y * a1 + cc1;
    ((float2*)buf)[r * 64 + cp] = v;
  }
}

// ---------------- launch ------------------------------------------------------
extern "C" void kernel_launch(void* const* d_in, const int* in_sizes, int n_in,
                              void* d_out, int out_size, void* d_ws, size_t ws_size,
                              hipStream_t stream) {
  const float* x_seq   = (const float*)d_in[0];
  const float* x_label = (const float*)d_in[1];
  const float* W1_bel  = (const float*)d_in[2];
  const float* b1_bel  = (const float*)d_in[3];
  const float* W1_inc  = (const float*)d_in[4];
  const float* b1_inc  = (const float*)d_in[5];
  const float* W1_con  = (const float*)d_in[6];
  const float* b1_con  = (const float*)d_in[7];
  const float* g1s     = (const float*)d_in[8];
  const float* beta1s  = (const float*)d_in[9];
  const float* g1l     = (const float*)d_in[10];
  const float* beta1l  = (const float*)d_in[11];
  const float* W2_bel  = (const float*)d_in[12];
  const float* b2_bel  = (const float*)d_in[13];
  const float* W2_inc  = (const float*)d_in[14];
  const float* b2_inc  = (const float*)d_in[15];
  const float* W2_con  = (const float*)d_in[16];
  const float* b2_con  = (const float*)d_in[17];
  const float* g2s     = (const float*)d_in[18];
  const float* beta2s  = (const float*)d_in[19];
  const float* g2l     = (const float*)d_in[20];
  const float* beta2l  = (const float*)d_in[21];
  const int* bel       = (const int*)d_in[22];
  const int* con_src   = (const int*)d_in[23];
  const int* con_dst   = (const int*)d_in[24];
  float* out = (float*)d_out;

  char* ws = (char*)d_ws;
  short*  aggbf    = (short*) (ws);                  // 25,600,000 B
  short*  h1pre    = (short*) (ws + 25600000);       // 25,600,000 B
  uint32* bpair    = (uint32*)(ws + 32000000);       //  8,028,160 B (dead after binB)
  int*    esrc     = (int*)   (ws + 51200000);       //  6,400,000 B
  // ---- zeroed region start (533,120 B) ----
  int*    deg_out    = (int*)  (ws + 57600000);      // 400,000 (aliased by dinv_out)
  int*    cnt_lab    = (int*)  (ws + 58000000);      //   1,024
  int*    bucket_cnt = (int*)  (ws + 58001024);      //   1,024
  float*  statsP1    = (float*)(ws + 58002048);      //  32,768 (32 x 256 f32)
  float*  statsP2    = (float*)(ws + 58034816);      //  32,768
  float*  lab_agg1   = (float*)(ws + 58067584);      //  32,768
  float*  lab_agg2   = (float*)(ws + 58100352);      //  32,768
  // ---- zeroed region end (58,133,120) ----
  float*  dinv_in    = (float*)(ws + 58133120);      // 400,000
  float*  dinv_cnt   = (float*)(ws + 58533120);      //     256
  int*    bbase      = (int*)  (ws + 58533376);      //   1,024
  int*    off        = (int*)  (ws + 58534400);      // 400,128
  float*  y_inc1     = (float*)(ws + 58934528);      //  32,768
  float*  y_inc2     = (float*)(ws + 58967296);      //  32,768
  float*  h_l1       = (float*)(ws + 59000064);      //  32,768
  short*  wT1        = (short*)(ws + 59032832);      //  32,768
  short*  wT2        = (short*)(ws + 59065600);      //  32,768
  int*    lab_base   = (int*)  (ws + 59098368);      //   1,024 (65 used)
  int*    lab_cursor = (int*)  (ws + 59099392);      //   1,024
  int*    lab_sorted = (int*)  (ws + 59100416);      // 400,000
  // end: 59,500,416 B

  float* dinv_out = (float*)deg_out;   // alias: deg_out dead after k_binB reads it
  uint32* xb = (uint32*)out;           // bf16 features in d_out[0..25.6MB)
  float* belp1 = (float*)ws;           // transient, overwritten by con_agg
  float* belp2 = (float*)ws;

  hipMemsetAsync(ws + 57600000, 0, 533120, stream);

  // CSR build + label sort + degrees + prep
  k_label_hist <<<256, 256, 0, stream>>>(bel, cnt_lab);
  k_binA       <<<(ECON + EPB - 1) / EPB, 256, 0, stream>>>(con_src, con_dst,
                                                            deg_out, bucket_cnt, bpair);
  k_bscan      <<<1, 256, 0, stream>>>(bucket_cnt, bbase, cnt_lab, dinv_cnt,
                                       lab_base, lab_cursor);
  k_binB       <<<NB, 256, 0, stream>>>(bpair, bucket_cnt, bbase, deg_out,
                                        off, dinv_in, dinv_out, esrc);
  k_lab_scatter<<<(NSEQ + RPB - 1) / RPB, 256, 0, stream>>>(bel, lab_cursor, lab_sorted);
  k_cast       <<<(NSEQ * D / 4 + 255) / 256, 256, 0, stream>>>(x_seq, xb);
  k_prep_w     <<<128, 256, 0, stream>>>(W1_con, W2_con, wT1, wT2);

  // ---- layer 1 ----
  k_lab_agg    <<<NLAB * 8, 256, 0, stream>>>(xb, lab_sorted, lab_base, lab_agg1);
  k_mm         <<<32, 256, 0, stream>>>(x_label, nullptr, W1_inc, nullptr, y_inc1, 128, 0);
  k_mm         <<<32, 256, 0, stream>>>(lab_agg1, dinv_cnt, W1_bel, b1_bel, belp1, 128, 1);
  k_label_bn   <<<1, 256, 0, stream>>>(belp1, g1l, beta1l, h_l1, 128);
  k_con_agg_bf <<<NSEQ / 4, 256, 0, stream>>>(xb, esrc, off, dinv_out, dinv_in,
                                              (uint32*)aggbf);
  k_gemm_mfma<1><<<(NSEQ + 63) / 64, 256, 0, stream>>>(
                   aggbf, wT1, b1_con, y_inc1, b1_inc, dinv_cnt, bel,
                   nullptr, h1pre, statsP1);
  k_bn_apply_bf<<<1024, 256, 0, stream>>>((uint32*)h1pre, statsP1, g1s, beta1s, xb);

  // ---- layer 2 ----
  k_lab_agg    <<<NLAB * 8, 256, 0, stream>>>(xb, lab_sorted, lab_base, lab_agg2);
  k_mm         <<<32, 256, 0, stream>>>(h_l1, nullptr, W2_inc, nullptr, y_inc2, 128, 0);
  k_mm         <<<16, 256, 0, stream>>>(lab_agg2, dinv_cnt, W2_bel, b2_bel, belp2, 64, 1);
  k_label_bn   <<<1, 256, 0, stream>>>(belp2, g2l, beta2l, out + (size_t)NSEQ * D, 64);
  k_con_agg_bf <<<NSEQ / 4, 256, 0, stream>>>(xb, esrc, off, dinv_out, dinv_in,
                                              (uint32*)aggbf);
  k_gemm_mfma<0><<<(NSEQ + 63) / 64, 256, 0, stream>>>(
                   aggbf, wT2, b2_con, y_inc2, b2_inc, dinv_cnt, bel,
                   out, nullptr, statsP2);
  k_bn_apply2  <<<1024, 256, 0, stream>>>(out, statsP2, g2s, beta2s);
}